// Round 2
// baseline (546.157 us; speedup 1.0000x reference)
//
#include <hip/hip_runtime.h>
#include <math.h>

// Problem constants
//   B=128, S=256, DIM=512, D=128, K=16384, grid 16x16 -> conv out 8x8 -> N=B*64=8192
#define NROWS 8192
#define KCB   16384

using frag_ab = __attribute__((ext_vector_type(8))) short;   // 8 bf16 (4 VGPR)
using frag_cd = __attribute__((ext_vector_type(4))) float;   // 4 fp32 acc
using f32x4   = __attribute__((ext_vector_type(4))) float;

__device__ inline unsigned short f2bf(float f) {             // RNE f32->bf16
    unsigned u = __float_as_uint(f);
    return (unsigned short)((u + 0x7FFFu + ((u >> 16) & 1u)) >> 16);
}

// ---------------------------------------------------------------------------
// k_wt: transpose conv_w [co][ci][kh][kw] -> W2 [(kh*3+kw)][ci][co]  (f32)
__global__ __launch_bounds__(256) void k_wt(const float* __restrict__ cw,
                                            float* __restrict__ W2) {
    int gid = blockIdx.x * 256 + threadIdx.x;     // 147456 total
    if (gid >= 147456) return;
    int co = gid & 127;
    int ci = (gid >> 7) & 127;
    int kk = gid >> 14;                           // 0..8
    W2[gid] = cw[(size_t)co * 1152 + ci * 9 + kk];
}

// ---------------------------------------------------------------------------
// k_c2: c2f[k] = sum_d cb[k][d]^2 + 1024  (bias keeps k_dist scores positive
// so raw float bits are a monotone sort key; k_refine never reads c2f)
__global__ __launch_bounds__(256) void k_c2(const float* __restrict__ cb,
                                            float* __restrict__ c2f) {
    int k = blockIdx.x * 256 + threadIdx.x;
    const float* row = cb + (size_t)k * 128;
    double s = 0.0;
    #pragma unroll
    for (int d = 0; d < 128; d += 4) {
        float4 v = *(const float4*)(row + d);
        s += (double)v.x * v.x + (double)v.y * v.y
           + (double)v.z * v.z + (double)v.w * v.w;
    }
    c2f[k] = (float)s + 1024.0f;
}

// ---------------------------------------------------------------------------
// k_cbbf: convert codebook f32 -> bf16 rows [16384][128]
__global__ __launch_bounds__(256) void k_cbbf(const float* __restrict__ cb,
                                              unsigned short* __restrict__ Cbb) {
    int gid = blockIdx.x * 256 + threadIdx.x;     // x4 elements, 524288 total
    float4 v = ((const float4*)cb)[gid];
    ushort4 o;
    o.x = f2bf(v.x); o.y = f2bf(v.y); o.z = f2bf(v.z); o.w = f2bf(v.w);
    ((ushort4*)Cbb)[gid] = o;
}

// ---------------------------------------------------------------------------
// k_encode_gemm: H = (last - first) @ W_in   (fp64 accumulate, serial d-order
// per output element -> bit-identical H to the proven baseline kernel).
// BM=32, BN=128, BK=16, 256 threads, grid 1024 -> 4 blocks/CU (~50% occ,
// was 21% grid-capped at 512 blocks). Thread tile 4 rows x 4 interleaved
// cols {tx, tx+32, tx+64, tx+96}: B-reads are stride-8B b64 (2-way alias,
// free) instead of 32B-strided 8-way conflicts. Bs staged as f64 (cvt
// hoisted out of the hot loop). LDS 21.2 KiB; pads kill staging conflicts.
__global__ __launch_bounds__(256) void k_encode_gemm(
    const float* __restrict__ last, const float* __restrict__ first,
    const float* __restrict__ W_in, double* __restrict__ H)
{
    __shared__ double As[16][34];    // [k][row]  4.35 KiB (pad +2)
    __shared__ double Bs[16][132];   // [k][col] 16.9 KiB (pad +4)
    const int tid  = threadIdx.x;
    const int row0 = blockIdx.x * 32;
    const int tx = tid & 31;         // cols tx + 32j, j=0..3
    const int ty = tid >> 5;         // rows ty*4 .. ty*4+3

    double acc[4][4];
    #pragma unroll
    for (int r = 0; r < 4; ++r)
        #pragma unroll
        for (int j = 0; j < 4; ++j) acc[r][j] = 0.0;

    const int abr = tid >> 2;            // A-stage row 0..31 (tid<128)
    const int abk = (tid & 3) << 2;      // A-stage k base 0,4,8,12
    const int bkk = tid >> 4;            // B-stage k 0..15
    const int bc  = (tid & 15) << 3;     // B-stage col base 0,8,...,120

    for (int k0 = 0; k0 < 512; k0 += 16) {
        if (k0) __syncthreads();
        if (tid < 128) {                 // stage A-diff (f64, transposed)
            const float4 l4 = *(const float4*)(last  + (size_t)(row0 + abr) * 512 + k0 + abk);
            const float4 f4 = *(const float4*)(first + (size_t)(row0 + abr) * 512 + k0 + abk);
            As[abk + 0][abr] = (double)l4.x - (double)f4.x;
            As[abk + 1][abr] = (double)l4.y - (double)f4.y;
            As[abk + 2][abr] = (double)l4.z - (double)f4.z;
            As[abk + 3][abr] = (double)l4.w - (double)f4.w;
        }
        {                                // stage B as f64: 16 k x 128 cols
            const float4 b0 = *(const float4*)(W_in + (size_t)(k0 + bkk) * 128 + bc);
            const float4 b1 = *(const float4*)(W_in + (size_t)(k0 + bkk) * 128 + bc + 4);
            *(double2*)&Bs[bkk][bc + 0] = make_double2((double)b0.x, (double)b0.y);
            *(double2*)&Bs[bkk][bc + 2] = make_double2((double)b0.z, (double)b0.w);
            *(double2*)&Bs[bkk][bc + 4] = make_double2((double)b1.x, (double)b1.y);
            *(double2*)&Bs[bkk][bc + 6] = make_double2((double)b1.z, (double)b1.w);
        }
        __syncthreads();
        #pragma unroll
        for (int d = 0; d < 16; ++d) {
            double2 a01 = *(const double2*)&As[d][ty * 4 + 0];   // broadcast
            double2 a23 = *(const double2*)&As[d][ty * 4 + 2];
            double a[4] = {a01.x, a01.y, a23.x, a23.y};
            double b[4];
            b[0] = Bs[d][tx];                                    // stride-8B
            b[1] = Bs[d][tx + 32];
            b[2] = Bs[d][tx + 64];
            b[3] = Bs[d][tx + 96];
            #pragma unroll
            for (int r = 0; r < 4; ++r)
                #pragma unroll
                for (int j = 0; j < 4; ++j)
                    acc[r][j] = fma(a[r], b[j], acc[r][j]);
        }
    }
    #pragma unroll
    for (int r = 0; r < 4; ++r) {
        double* o = H + (size_t)(row0 + ty * 4 + r) * 128 + tx;
        o[0]  = acc[r][0];
        o[32] = acc[r][1];
        o[64] = acc[r][2];
        o[96] = acc[r][3];
    }
}

// ---------------------------------------------------------------------------
// k_conv: 3x3 stride-2 pad-1 conv (no bias; cancels), fp64.
// Writes X (f64, for refine/quantize) and Xb (bf16, for MFMA candidate sweep).
__global__ __launch_bounds__(256) void k_conv(
    const double* __restrict__ H, const float* __restrict__ W2,
    double* __restrict__ X, unsigned short* __restrict__ Xb)
{
    __shared__ double Hs[3 * 16 * 128];             // [kh][iw][ci]  48 KiB
    const int b   = blockIdx.x >> 3;
    const int oh  = blockIdx.x & 7;
    const int tid = threadIdx.x;
    const int ih0 = 2 * oh - 1;
    for (int it = 0; it < 24; ++it) {
        int idx = it * 256 + tid;                   // 6144 doubles
        int r = idx >> 11;
        int rem = idx & 2047;
        int ih = ih0 + r;
        Hs[idx] = (ih >= 0) ? H[(size_t)b * 32768 + (size_t)ih * 2048 + rem] : 0.0;
    }
    __syncthreads();
    const int co   = tid & 127;
    const int half = tid >> 7;                      // ow in [half*4, half*4+3]
    const int iwb  = half * 8 - 1;
    double acc[4] = {0, 0, 0, 0};
    for (int ci = 0; ci < 128; ++ci) {
        #pragma unroll
        for (int kh = 0; kh < 3; ++kh) {
            double in[9];
            #pragma unroll
            for (int t = 0; t < 9; ++t) {
                int iw = iwb + t;
                in[t] = (iw >= 0) ? Hs[kh * 2048 + iw * 128 + ci] : 0.0;
            }
            #pragma unroll
            for (int kw = 0; kw < 3; ++kw) {
                double w = (double)W2[(size_t)((kh * 3 + kw) * 128 + ci) * 128 + co];
                #pragma unroll
                for (int i = 0; i < 4; ++i)
                    acc[i] = fma(in[2 * i + kw], w, acc[i]);
            }
        }
    }
    #pragma unroll
    for (int i = 0; i < 4; ++i) {
        int ow = half * 4 + i;
        size_t n = (size_t)b * 64 + oh * 8 + ow;
        X [n * 128 + co] = acc[i];
        Xb[n * 128 + co] = f2bf((float)acc[i]);
    }
}

// ---------------------------------------------------------------------------
// k_dist_mfma: bf16 MFMA candidate sweep. Block = 128 rows x 2048-code split;
// grid (64, 8) = 512 blocks (2/CU). Per chunk of 128 codes: 16x16x32 MFMA,
// codes as M, rows as N (D: col=lane&15=row, row=quad*4+reg=code).
// LDS exactly 64 KiB; 16B chunks XOR-swizzled (ch ^= row&15) -> conflict-free.
// Selection: score u = (||c||^2+1024) - 2 x.c > 0; sortable uint key =
// (bits(u) & ~0x7FF) | split-local code idx (11 bits); top-2 per (lane,row)
// class via min/max (no cndmask), then per-row top-2 of 16 via LDS.
// Coverage: bf16 noise sigma~0.05 + trunc <0.5 vs rank gaps ~7-20 -> safe;
// fp64 k_refine picks the exact argmin among the 16 candidates.
__global__ __launch_bounds__(256) void k_dist_mfma(
    const unsigned short* __restrict__ Xb, const unsigned short* __restrict__ Cbb,
    const float* __restrict__ c2f, int* __restrict__ cand)
{
    __shared__ __align__(16) unsigned short Xs[128 * 128];   // 32 KiB
    __shared__ __align__(16) unsigned short Cs[128 * 128];   // 32 KiB
    const int tid   = threadIdx.x;
    const int row0  = blockIdx.x * 128;
    const int split = blockIdx.y;
    const int lane  = tid & 63;
    const int w     = tid >> 6;
    const int quad  = lane >> 4;
    const int lm    = lane & 15;
    const int cw    = (w & 1) * 64;       // wave's code sub-tile
    const int rw    = (w >> 1) * 64;      // wave's row sub-tile

    #pragma unroll
    for (int it = 0; it < 8; ++it) {      // stage X tile once (swizzled)
        int flat = it * 256 + tid;
        int r = flat >> 4, ch = flat & 15;
        *(uint4*)&Xs[r * 128 + (((ch ^ r) & 15) << 3) + (ch & 16 ? 0 : 0)] =
            *(const uint4*)(Xb + (size_t)(row0 + r) * 128 + ch * 8);
    }

    unsigned k1[4], k2[4];
    #pragma unroll
    for (int j = 0; j < 4; ++j) { k1[j] = 0xFFFFFFFFu; k2[j] = 0xFFFFFFFFu; }

    for (int chunk = 0; chunk < 16; ++chunk) {
        const int kb = split * 2048 + chunk * 128;
        if (chunk) __syncthreads();
        #pragma unroll
        for (int it = 0; it < 8; ++it) {  // stage code chunk (swizzled)
            int flat = it * 256 + tid;
            int r = flat >> 4, ch = flat & 15;
            *(uint4*)&Cs[r * 128 + ((ch ^ (r & 15)) << 3)] =
                *(const uint4*)(Cbb + (size_t)(kb + r) * 128 + ch * 8);
        }
        __syncthreads();

        frag_cd acc[4][4];
        #pragma unroll
        for (int i = 0; i < 4; ++i)
            #pragma unroll
            for (int j = 0; j < 4; ++j)
                #pragma unroll
                for (int r = 0; r < 4; ++r) acc[i][j][r] = 0.f;

        #pragma unroll
        for (int kk = 0; kk < 4; ++kk) {
            const int chs = ((kk * 4 + quad) ^ lm) << 3;
            frag_ab a[4], b[4];
            #pragma unroll
            for (int i = 0; i < 4; ++i)
                a[i] = *(const frag_ab*)&Cs[(cw + i * 16 + lm) * 128 + chs];
            #pragma unroll
            for (int j = 0; j < 4; ++j)
                b[j] = *(const frag_ab*)&Xs[(rw + j * 16 + lm) * 128 + chs];
            #pragma unroll
            for (int i = 0; i < 4; ++i)
                #pragma unroll
                for (int j = 0; j < 4; ++j)
                    acc[i][j] = __builtin_amdgcn_mfma_f32_16x16x32_bf16(
                        a[i], b[j], acc[i][j], 0, 0, 0);
        }

        const int ib = chunk * 128 + cw + quad * 4;   // split-local idx base
        #pragma unroll
        for (int i = 0; i < 4; ++i) {
            f32x4 c2v = *(const f32x4*)(c2f + kb + cw + i * 16 + quad * 4);
            #pragma unroll
            for (int j = 0; j < 4; ++j) {
                #pragma unroll
                for (int r = 0; r < 4; ++r) {
                    float u = fmaf(-2.f, acc[i][j][r], c2v[r]);
                    unsigned key = (__float_as_uint(u) & 0xFFFFF800u)
                                 | (unsigned)(ib + i * 16 + r);
                    unsigned nk1 = min(key, k1[j]);
                    k2[j] = min(max(key, k1[j]), k2[j]);
                    k1[j] = nk1;
                }
            }
        }
    }

    // per-row reduce: 8 slots x 2 keys -> top-2 of the split
    __syncthreads();
    uint2* kred = (uint2*)Cs;             // [128 rows][8 slots]
    #pragma unroll
    for (int j = 0; j < 4; ++j)
        kred[(rw + j * 16 + lm) * 8 + (w & 1) * 4 + quad] = make_uint2(k1[j], k2[j]);
    __syncthreads();
    if (tid < 128) {
        unsigned b1 = 0xFFFFFFFFu, b2 = 0xFFFFFFFFu;
        for (int e = 0; e < 8; ++e) {
            uint2 kv = kred[tid * 8 + e];
            unsigned n1 = min(kv.x, b1); b2 = min(max(kv.x, b1), b2); b1 = n1;
            n1 = min(kv.y, b1);          b2 = min(max(kv.y, b1), b2); b1 = n1;
        }
        int base = split * 2048;
        int* o = cand + (size_t)(row0 + tid) * 16 + split * 2;
        o[0] = base + (int)(b1 & 0x7FFu);
        o[1] = base + (int)(b2 & 0x7FFu);
    }
}

// ---------------------------------------------------------------------------
// k_refine: fp64-exact argmin over 16 candidates; quantize; counts; indices.
__global__ __launch_bounds__(256) void k_refine(
    const double* __restrict__ X, const float* __restrict__ cb,
    const int* __restrict__ cand, const float* __restrict__ rnd,
    int* __restrict__ counts, float* __restrict__ quant,
    float* __restrict__ out_mi)
{
    const int wid  = threadIdx.x >> 6;
    const int lane = threadIdx.x & 63;
    const int row  = blockIdx.x * 4 + wid;
    const double x0 = X[(size_t)row * 128 + lane];
    const double x1 = X[(size_t)row * 128 + 64 + lane];
    double bestv = 1e300; int bestk = 0;
    for (int c = 0; c < 16; ++c) {
        int k = cand[(size_t)row * 16 + c] & (KCB - 1);   // defensive clamp
        double t0 = x0 - (double)cb[(size_t)k * 128 + lane];
        double t1 = x1 - (double)cb[(size_t)k * 128 + 64 + lane];
        double s = t0 * t0 + t1 * t1;
        #pragma unroll
        for (int off = 32; off > 0; off >>= 1) s += __shfl_xor(s, off, 64);
        if (s < bestv) { bestv = s; bestk = k; }
    }
    double r0 = (double)rnd[(size_t)row * 128 + lane];
    double r1 = (double)rnd[(size_t)row * 128 + 64 + lane];
    double rs = r0 * r0 + r1 * r1;
    #pragma unroll
    for (int off = 32; off > 0; off >>= 1) rs += __shfl_xor(rs, off, 64);
    double ratio = sqrt(bestv) / sqrt(rs) + 1e-12;
    quant[(size_t)row * 128 + lane]      = (float)(x0 + ratio * r0);
    quant[(size_t)row * 128 + 64 + lane] = (float)(x1 + ratio * r1);
    if (lane == 0) {
        out_mi[row] = (float)bestk;
        atomicAdd(counts + bestk, 1);
    }
}

// ---------------------------------------------------------------------------
// k_perplex: perplexity + new_used (single block)
__global__ __launch_bounds__(256) void k_perplex(
    const int* __restrict__ counts, const int* __restrict__ used_in,
    float* __restrict__ out_used, float* __restrict__ out_perp)
{
    __shared__ double red[256];
    int tid = threadIdx.x;
    double e = 0.0;
    for (int k = tid; k < KCB; k += 256) {
        int c = counts[k];
        out_used[k] = (float)(used_in[k] + c);
        if (c > 0) {
            double p = (double)c / 8192.0;
            e += p * log(p + 1e-12);
        }
    }
    red[tid] = e;
    __syncthreads();
    for (int s = 128; s > 0; s >>= 1) {
        if (tid < s) red[tid] += red[tid + s];
        __syncthreads();
    }
    if (tid == 0) out_perp[0] = (float)exp(-red[0]);
}

// ---------------------------------------------------------------------------
// k_decode: out[b,s2,m] = sum_d2 quant[b*8192 + d2*64 + s2] * W_out[d2,m] + b_out[m]
__global__ __launch_bounds__(256) void k_decode(
    const float* __restrict__ quant, const float* __restrict__ W_out,
    const float* __restrict__ b_out, float* __restrict__ out)
{
    __shared__ float As[8192];             // [d2][s2] (raw reinterpretation!)
    __shared__ float Bs[8192];             // [d2][64 m]
    const int tid = threadIdx.x;
    const int m0  = blockIdx.x * 64;
    const int b   = blockIdx.y;
    #pragma unroll
    for (int it = 0; it < 8; ++it) {
        int flat = it * 1024 + tid * 4;
        *(float4*)&As[flat] = *(const float4*)(quant + (size_t)b * 8192 + flat);
        int d2 = flat >> 6, m = flat & 63;
        *(float4*)&Bs[flat] = *(const float4*)(W_out + (size_t)d2 * 512 + m0 + m);
    }
    __syncthreads();
    const int tx = tid & 15, ty = tid >> 4;
    float acc[4][4];
    #pragma unroll
    for (int i = 0; i < 4; ++i)
        #pragma unroll
        for (int j = 0; j < 4; ++j) acc[i][j] = 0.f;
    #pragma unroll 8
    for (int d2 = 0; d2 < 128; ++d2) {
        float4 a  = *(const float4*)&As[d2 * 64 + ty * 4];
        float4 b4 = *(const float4*)&Bs[d2 * 64 + tx * 4];
        float av[4] = {a.x, a.y, a.z, a.w};
        float bv[4] = {b4.x, b4.y, b4.z, b4.w};
        #pragma unroll
        for (int i = 0; i < 4; ++i)
            #pragma unroll
            for (int j = 0; j < 4; ++j)
                acc[i][j] = fmaf(av[i], bv[j], acc[i][j]);
    }
    float4 bo = *(const float4*)(b_out + m0 + tx * 4);
    float bob[4] = {bo.x, bo.y, bo.z, bo.w};
    #pragma unroll
    for (int i = 0; i < 4; ++i) {
        int s2 = ty * 4 + i;
        float4 o;
        o.x = acc[i][0] + bob[0];
        o.y = acc[i][1] + bob[1];
        o.z = acc[i][2] + bob[2];
        o.w = acc[i][3] + bob[3];
        *(float4*)(out + (size_t)b * 32768 + (size_t)s2 * 512 + m0 + tx * 4) = o;
    }
}

// ---------------------------------------------------------------------------
extern "C" void kernel_launch(void* const* d_in, const int* in_sizes, int n_in,
                              void* d_out, int out_size, void* d_ws, size_t ws_size,
                              hipStream_t stream) {
    const float* first  = (const float*)d_in[0];
    const float* last   = (const float*)d_in[1];
    const float* rnd    = (const float*)d_in[2];
    const float* cb     = (const float*)d_in[3];
    const float* W_in   = (const float*)d_in[4];
    const float* conv_w = (const float*)d_in[6];
    const float* W_out  = (const float*)d_in[8];
    const float* b_out  = (const float*)d_in[9];
    const int*   used   = (const int*)d_in[10];

    float* out      = (float*)d_out;
    float* out_perp = out + 4194304;               // B*64*DIM
    float* out_used = out + 4194305;
    float* out_mi   = out + 4194305 + 16384;

    char* ws = (char*)d_ws;
    double*         H      = (double*)(ws);                 // 33,554,432 B
    double*         X      = (double*)(ws + 33554432);      //  8,388,608 B
    unsigned short* Cbb    = (unsigned short*)(ws + 41943040); // 4,194,304 B
    float*          W2     = (float*) (ws + 46137344);      //    589,824 B
    float*          c2f    = (float*) (ws + 46727168);      //     65,536 B
    int*            cand   = (int*)   (ws + 46792704);      //    524,288 B
    float*          quant  = (float*) (ws + 47316992);      //  4,194,304 B
    int*            counts = (int*)   (ws + 51511296);      //     65,536 B
    unsigned short* Xb     = (unsigned short*)(ws + 51576832); // 2,097,152 B
                                                            // total 53,673,984 B

    hipMemsetAsync(counts, 0, KCB * sizeof(int), stream);
    k_wt<<<576, 256, 0, stream>>>(conv_w, W2);
    k_c2<<<64, 256, 0, stream>>>(cb, c2f);
    k_cbbf<<<2048, 256, 0, stream>>>(cb, Cbb);
    k_encode_gemm<<<1024, 256, 0, stream>>>(last, first, W_in, H);
    k_conv<<<1024, 256, 0, stream>>>(H, W2, X, Xb);
    k_dist_mfma<<<dim3(64, 8), 256, 0, stream>>>(Xb, Cbb, c2f, cand);
    k_refine<<<2048, 256, 0, stream>>>(X, cb, cand, rnd, counts, quant, out_mi);
    k_perplex<<<1, 256, 0, stream>>>(counts, used, out_used, out_perp);
    k_decode<<<dim3(8, 128), 256, 0, stream>>>(quant, W_out, b_out, out);
}

// Round 3
// 504.192 us; speedup vs baseline: 1.0832x; 1.0832x over previous
//
#include <hip/hip_runtime.h>
#include <math.h>

// Problem constants
//   B=128, S=256, DIM=512, D=128, K=16384, grid 16x16 -> conv out 8x8 -> N=B*64=8192
#define NROWS 8192
#define KCB   16384

using frag_ab = __attribute__((ext_vector_type(8))) short;   // 8 bf16 (4 VGPR)
using frag_cd = __attribute__((ext_vector_type(4))) float;   // 4 fp32 acc
using f32x4   = __attribute__((ext_vector_type(4))) float;
using f64x4   = __attribute__((ext_vector_type(4))) double;  // fp64 MFMA acc

__device__ inline unsigned short f2bf(float f) {             // RNE f32->bf16
    unsigned u = __float_as_uint(f);
    return (unsigned short)((u + 0x7FFFu + ((u >> 16) & 1u)) >> 16);
}

// ---------------------------------------------------------------------------
// k_wt: transpose conv_w [co][ci][kh][kw] -> W2 [(kh*3+kw)][ci][co]  (f32)
__global__ __launch_bounds__(256) void k_wt(const float* __restrict__ cw,
                                            float* __restrict__ W2) {
    int gid = blockIdx.x * 256 + threadIdx.x;     // 147456 total
    if (gid >= 147456) return;
    int co = gid & 127;
    int ci = (gid >> 7) & 127;
    int kk = gid >> 14;                           // 0..8
    W2[gid] = cw[(size_t)co * 1152 + ci * 9 + kk];
}

// ---------------------------------------------------------------------------
// k_c2: c2f[k] = sum_d cb[k][d]^2 + 1024  (bias keeps k_dist scores positive
// so raw float bits are a monotone sort key; k_refine never reads c2f)
__global__ __launch_bounds__(256) void k_c2(const float* __restrict__ cb,
                                            float* __restrict__ c2f) {
    int k = blockIdx.x * 256 + threadIdx.x;
    const float* row = cb + (size_t)k * 128;
    double s = 0.0;
    #pragma unroll
    for (int d = 0; d < 128; d += 4) {
        float4 v = *(const float4*)(row + d);
        s += (double)v.x * v.x + (double)v.y * v.y
           + (double)v.z * v.z + (double)v.w * v.w;
    }
    c2f[k] = (float)s + 1024.0f;
}

// ---------------------------------------------------------------------------
// k_cbbf: convert codebook f32 -> bf16 rows [16384][128]
__global__ __launch_bounds__(256) void k_cbbf(const float* __restrict__ cb,
                                              unsigned short* __restrict__ Cbb) {
    int gid = blockIdx.x * 256 + threadIdx.x;     // x4 elements, 524288 total
    float4 v = ((const float4*)cb)[gid];
    ushort4 o;
    o.x = f2bf(v.x); o.y = f2bf(v.y); o.z = f2bf(v.z); o.w = f2bf(v.w);
    ((ushort4*)Cbb)[gid] = o;
}

// ---------------------------------------------------------------------------
// k_encode_gemm: H = (last - first) @ W_in, fp64 via v_mfma_f64_16x16x4.
// M=32768, N=128, K=512. Block = 4 waves, tile BM=64 x BN=128, BK=32,
// grid 512 (2 blocks/CU). Wave w: wm=(w&1)*32 (2 m-frags), wn=(w>>1)*64
// (4 n-frags) -> 8 f64x4 accs.
//
// LAYOUT SELF-PROBE (round-1 failed with assumed layout -> index flips):
// 3 probe MFMAs decode the true per-lane/slot (m,n) of the D fragment:
//   d1 = mfma(lane, 1):  d1[s] = 4*m_s + 96   (rowsum of lane-id A)
//   d2 = mfma(1, lane):  d2[s] = 4*n_s + 96   (colsum of lane-id B)
//   d3 = mfma(16^kq, lane): must equal 4369*n_s + 205056 (k-pairing check)
// The decode is self-consistent under any operand-swap/transpose since the
// GEMM uses identical conventions (first arg <- As[k][wm+lm], k=lane>>4).
// Any check failure -> proven scalar-FMA fallback path (same LDS, same
// epilogue with assumed pm=4*kq+s, pn=lm). fp64 K-reassociation is safe:
// top-2 distance gaps ~O(1) >> 1e-12 noise.
__global__ __launch_bounds__(256) void k_encode_gemm(
    const float* __restrict__ last, const float* __restrict__ first,
    const float* __restrict__ W_in, double* __restrict__ H)
{
    __shared__ double As[32][66];    // [k][row] 16.5 KiB (pad 64->66)
    __shared__ double Bs[32][132];   // [k][col] 33.0 KiB (pad 128->132)
    const int tid  = threadIdx.x;
    const int lane = tid & 63;
    const int w    = tid >> 6;
    const int row0 = blockIdx.x * 64;
    const int wm   = (w & 1) * 32;
    const int wn   = (w >> 1) * 64;
    const int lm   = lane & 15;
    const int kq   = lane >> 4;

    // ---- layout probe ----
    f64x4 z; z[0] = 0.0; z[1] = 0.0; z[2] = 0.0; z[3] = 0.0;
    const double dl = (double)lane;
    f64x4 d1 = __builtin_amdgcn_mfma_f64_16x16x4f64(dl, 1.0, z, 0, 0, 0);
    f64x4 d2 = __builtin_amdgcn_mfma_f64_16x16x4f64(1.0, dl, z, 0, 0, 0);
    const double pk = (double)(1 << (4 * kq));         // 16^kq
    f64x4 d3 = __builtin_amdgcn_mfma_f64_16x16x4f64(pk, dl, z, 0, 0, 0);
    int pm[4], pn[4];
    int okl = 1;
    #pragma unroll
    for (int s = 0; s < 4; ++s) {
        double v1 = d1[s] - 96.0, v2 = d2[s] - 96.0;
        int i1 = (int)v1, i2 = (int)v2;
        okl &= (d1[s] == (double)(96 + i1)) & (i1 >= 0) & (i1 < 64) & ((i1 & 3) == 0);
        okl &= (d2[s] == (double)(96 + i2)) & (i2 >= 0) & (i2 < 64) & ((i2 & 3) == 0);
        pm[s] = i1 >> 2;
        pn[s] = i2 >> 2;
        okl &= (d3[s] == 4369.0 * (double)pn[s] + 205056.0);
    }
    const int ok = __all(okl);
    if (!ok) {
        #pragma unroll
        for (int s = 0; s < 4; ++s) { pm[s] = 4 * kq + s; pn[s] = lm; }
    }

    f64x4 acc[2][4];
    #pragma unroll
    for (int i = 0; i < 2; ++i)
        #pragma unroll
        for (int j = 0; j < 4; ++j)
            #pragma unroll
            for (int q = 0; q < 4; ++q) acc[i][j][q] = 0.0;

    const int ar = tid >> 2;             // A-stage: row 0..63
    const int ak = (tid & 3) * 8;        // A-stage: k base 0,8,16,24
    const int bkk = tid >> 3;            // B-stage: k 0..31
    const int bc  = (tid & 7) * 16;      // B-stage: col base 0..112

    for (int k0 = 0; k0 < 512; k0 += 32) {
        if (k0) __syncthreads();
        {   // stage A-diff (f64, transposed): 64 rows x 32 k
            const float* lp = last  + (size_t)(row0 + ar) * 512 + k0 + ak;
            const float* fp = first + (size_t)(row0 + ar) * 512 + k0 + ak;
            const float4 l0 = *(const float4*)(lp);
            const float4 l1 = *(const float4*)(lp + 4);
            const float4 f0 = *(const float4*)(fp);
            const float4 f1 = *(const float4*)(fp + 4);
            As[ak + 0][ar] = (double)l0.x - (double)f0.x;
            As[ak + 1][ar] = (double)l0.y - (double)f0.y;
            As[ak + 2][ar] = (double)l0.z - (double)f0.z;
            As[ak + 3][ar] = (double)l0.w - (double)f0.w;
            As[ak + 4][ar] = (double)l1.x - (double)f1.x;
            As[ak + 5][ar] = (double)l1.y - (double)f1.y;
            As[ak + 6][ar] = (double)l1.z - (double)f1.z;
            As[ak + 7][ar] = (double)l1.w - (double)f1.w;
        }
        {   // stage B (f64): 32 k x 128 cols
            const float* wp = W_in + (size_t)(k0 + bkk) * 128 + bc;
            #pragma unroll
            for (int q = 0; q < 4; ++q) {
                const float4 b4 = *(const float4*)(wp + 4 * q);
                Bs[bkk][bc + 4 * q + 0] = (double)b4.x;
                Bs[bkk][bc + 4 * q + 1] = (double)b4.y;
                Bs[bkk][bc + 4 * q + 2] = (double)b4.z;
                Bs[bkk][bc + 4 * q + 3] = (double)b4.w;
            }
        }
        __syncthreads();
        if (ok) {
            #pragma unroll
            for (int kc = 0; kc < 8; ++kc) {
                const int kk = kc * 4 + kq;
                double a0 = As[kk][wm + lm];
                double a1 = As[kk][wm + 16 + lm];
                double b0 = Bs[kk][wn + lm];
                double b1 = Bs[kk][wn + 16 + lm];
                double b2 = Bs[kk][wn + 32 + lm];
                double b3 = Bs[kk][wn + 48 + lm];
                acc[0][0] = __builtin_amdgcn_mfma_f64_16x16x4f64(a0, b0, acc[0][0], 0, 0, 0);
                acc[0][1] = __builtin_amdgcn_mfma_f64_16x16x4f64(a0, b1, acc[0][1], 0, 0, 0);
                acc[0][2] = __builtin_amdgcn_mfma_f64_16x16x4f64(a0, b2, acc[0][2], 0, 0, 0);
                acc[0][3] = __builtin_amdgcn_mfma_f64_16x16x4f64(a0, b3, acc[0][3], 0, 0, 0);
                acc[1][0] = __builtin_amdgcn_mfma_f64_16x16x4f64(a1, b0, acc[1][0], 0, 0, 0);
                acc[1][1] = __builtin_amdgcn_mfma_f64_16x16x4f64(a1, b1, acc[1][1], 0, 0, 0);
                acc[1][2] = __builtin_amdgcn_mfma_f64_16x16x4f64(a1, b2, acc[1][2], 0, 0, 0);
                acc[1][3] = __builtin_amdgcn_mfma_f64_16x16x4f64(a1, b3, acc[1][3], 0, 0, 0);
            }
        } else {
            #pragma unroll 4
            for (int k = 0; k < 32; ++k) {
                double b0 = Bs[k][wn + lm];
                double b1 = Bs[k][wn + 16 + lm];
                double b2 = Bs[k][wn + 32 + lm];
                double b3 = Bs[k][wn + 48 + lm];
                #pragma unroll
                for (int i = 0; i < 2; ++i) {
                    const double* ap = &As[k][wm + i * 16 + 4 * kq];
                    #pragma unroll
                    for (int s = 0; s < 4; ++s) {
                        double a = ap[s];
                        acc[i][0][s] = fma(a, b0, acc[i][0][s]);
                        acc[i][1][s] = fma(a, b1, acc[i][1][s]);
                        acc[i][2][s] = fma(a, b2, acc[i][2][s]);
                        acc[i][3][s] = fma(a, b3, acc[i][3][s]);
                    }
                }
            }
        }
    }
    #pragma unroll
    for (int i = 0; i < 2; ++i)
        #pragma unroll
        for (int j = 0; j < 4; ++j)
            #pragma unroll
            for (int s = 0; s < 4; ++s)
                H[(size_t)(row0 + wm + i * 16 + pm[s]) * 128 + wn + j * 16 + pn[s]]
                    = acc[i][j][s];
}

// ---------------------------------------------------------------------------
// k_conv: 3x3 stride-2 pad-1 conv (no bias; cancels), fp64.
// Writes X (f64, for refine/quantize) and Xb (bf16, for MFMA candidate sweep).
__global__ __launch_bounds__(256) void k_conv(
    const double* __restrict__ H, const float* __restrict__ W2,
    double* __restrict__ X, unsigned short* __restrict__ Xb)
{
    __shared__ double Hs[3 * 16 * 128];             // [kh][iw][ci]  48 KiB
    const int b   = blockIdx.x >> 3;
    const int oh  = blockIdx.x & 7;
    const int tid = threadIdx.x;
    const int ih0 = 2 * oh - 1;
    for (int it = 0; it < 24; ++it) {
        int idx = it * 256 + tid;                   // 6144 doubles
        int r = idx >> 11;
        int rem = idx & 2047;
        int ih = ih0 + r;
        Hs[idx] = (ih >= 0) ? H[(size_t)b * 32768 + (size_t)ih * 2048 + rem] : 0.0;
    }
    __syncthreads();
    const int co   = tid & 127;
    const int half = tid >> 7;                      // ow in [half*4, half*4+3]
    const int iwb  = half * 8 - 1;
    double acc[4] = {0, 0, 0, 0};
    for (int ci = 0; ci < 128; ++ci) {
        #pragma unroll
        for (int kh = 0; kh < 3; ++kh) {
            double in[9];
            #pragma unroll
            for (int t = 0; t < 9; ++t) {
                int iw = iwb + t;
                in[t] = (iw >= 0) ? Hs[kh * 2048 + iw * 128 + ci] : 0.0;
            }
            #pragma unroll
            for (int kw = 0; kw < 3; ++kw) {
                double w = (double)W2[(size_t)((kh * 3 + kw) * 128 + ci) * 128 + co];
                #pragma unroll
                for (int i = 0; i < 4; ++i)
                    acc[i] = fma(in[2 * i + kw], w, acc[i]);
            }
        }
    }
    #pragma unroll
    for (int i = 0; i < 4; ++i) {
        int ow = half * 4 + i;
        size_t n = (size_t)b * 64 + oh * 8 + ow;
        X [n * 128 + co] = acc[i];
        Xb[n * 128 + co] = f2bf((float)acc[i]);
    }
}

// ---------------------------------------------------------------------------
// k_dist_mfma: bf16 MFMA candidate sweep. Block = 128 rows x 2048-code split;
// grid (64, 8) = 512 blocks (2/CU). Per chunk of 128 codes: 16x16x32 MFMA,
// codes as M, rows as N (D: col=lane&15=row, row=quad*4+reg=code).
// LDS exactly 64 KiB; 16B chunks XOR-swizzled (ch ^= row&15) -> conflict-free.
// Selection: score u = (||c||^2+1024) - 2 x.c > 0; sortable uint key =
// (bits(u) & ~0x7FF) | split-local code idx (11 bits); top-2 per (lane,row)
// class via min/max (no cndmask), then per-row top-2 of 16 via LDS.
// Coverage: bf16 noise sigma~0.05 + trunc <0.5 vs rank gaps ~7-20 -> safe;
// fp64 k_refine picks the exact argmin among the 16 candidates.
__global__ __launch_bounds__(256) void k_dist_mfma(
    const unsigned short* __restrict__ Xb, const unsigned short* __restrict__ Cbb,
    const float* __restrict__ c2f, int* __restrict__ cand)
{
    __shared__ __align__(16) unsigned short Xs[128 * 128];   // 32 KiB
    __shared__ __align__(16) unsigned short Cs[128 * 128];   // 32 KiB
    const int tid   = threadIdx.x;
    const int row0  = blockIdx.x * 128;
    const int split = blockIdx.y;
    const int lane  = tid & 63;
    const int w     = tid >> 6;
    const int quad  = lane >> 4;
    const int lm    = lane & 15;
    const int cw    = (w & 1) * 64;       // wave's code sub-tile
    const int rw    = (w >> 1) * 64;      // wave's row sub-tile

    #pragma unroll
    for (int it = 0; it < 8; ++it) {      // stage X tile once (swizzled)
        int flat = it * 256 + tid;
        int r = flat >> 4, ch = flat & 15;
        *(uint4*)&Xs[r * 128 + (((ch ^ r) & 15) << 3) + (ch & 16 ? 0 : 0)] =
            *(const uint4*)(Xb + (size_t)(row0 + r) * 128 + ch * 8);
    }

    unsigned k1[4], k2[4];
    #pragma unroll
    for (int j = 0; j < 4; ++j) { k1[j] = 0xFFFFFFFFu; k2[j] = 0xFFFFFFFFu; }

    for (int chunk = 0; chunk < 16; ++chunk) {
        const int kb = split * 2048 + chunk * 128;
        if (chunk) __syncthreads();
        #pragma unroll
        for (int it = 0; it < 8; ++it) {  // stage code chunk (swizzled)
            int flat = it * 256 + tid;
            int r = flat >> 4, ch = flat & 15;
            *(uint4*)&Cs[r * 128 + ((ch ^ (r & 15)) << 3)] =
                *(const uint4*)(Cbb + (size_t)(kb + r) * 128 + ch * 8);
        }
        __syncthreads();

        frag_cd acc[4][4];
        #pragma unroll
        for (int i = 0; i < 4; ++i)
            #pragma unroll
            for (int j = 0; j < 4; ++j)
                #pragma unroll
                for (int r = 0; r < 4; ++r) acc[i][j][r] = 0.f;

        #pragma unroll
        for (int kk = 0; kk < 4; ++kk) {
            const int chs = ((kk * 4 + quad) ^ lm) << 3;
            frag_ab a[4], b[4];
            #pragma unroll
            for (int i = 0; i < 4; ++i)
                a[i] = *(const frag_ab*)&Cs[(cw + i * 16 + lm) * 128 + chs];
            #pragma unroll
            for (int j = 0; j < 4; ++j)
                b[j] = *(const frag_ab*)&Xs[(rw + j * 16 + lm) * 128 + chs];
            #pragma unroll
            for (int i = 0; i < 4; ++i)
                #pragma unroll
                for (int j = 0; j < 4; ++j)
                    acc[i][j] = __builtin_amdgcn_mfma_f32_16x16x32_bf16(
                        a[i], b[j], acc[i][j], 0, 0, 0);
        }

        const int ib = chunk * 128 + cw + quad * 4;   // split-local idx base
        #pragma unroll
        for (int i = 0; i < 4; ++i) {
            f32x4 c2v = *(const f32x4*)(c2f + kb + cw + i * 16 + quad * 4);
            #pragma unroll
            for (int j = 0; j < 4; ++j) {
                #pragma unroll
                for (int r = 0; r < 4; ++r) {
                    float u = fmaf(-2.f, acc[i][j][r], c2v[r]);
                    unsigned key = (__float_as_uint(u) & 0xFFFFF800u)
                                 | (unsigned)(ib + i * 16 + r);
                    unsigned nk1 = min(key, k1[j]);
                    k2[j] = min(max(key, k1[j]), k2[j]);
                    k1[j] = nk1;
                }
            }
        }
    }

    // per-row reduce: 8 slots x 2 keys -> top-2 of the split
    __syncthreads();
    uint2* kred = (uint2*)Cs;             // [128 rows][8 slots]
    #pragma unroll
    for (int j = 0; j < 4; ++j)
        kred[(rw + j * 16 + lm) * 8 + (w & 1) * 4 + quad] = make_uint2(k1[j], k2[j]);
    __syncthreads();
    if (tid < 128) {
        unsigned b1 = 0xFFFFFFFFu, b2 = 0xFFFFFFFFu;
        for (int e = 0; e < 8; ++e) {
            uint2 kv = kred[tid * 8 + e];
            unsigned n1 = min(kv.x, b1); b2 = min(max(kv.x, b1), b2); b1 = n1;
            n1 = min(kv.y, b1);          b2 = min(max(kv.y, b1), b2); b1 = n1;
        }
        int base = split * 2048;
        int* o = cand + (size_t)(row0 + tid) * 16 + split * 2;
        o[0] = base + (int)(b1 & 0x7FFu);
        o[1] = base + (int)(b2 & 0x7FFu);
    }
}

// ---------------------------------------------------------------------------
// k_refine: fp64-exact argmin over 16 candidates; quantize; counts; indices.
__global__ __launch_bounds__(256) void k_refine(
    const double* __restrict__ X, const float* __restrict__ cb,
    const int* __restrict__ cand, const float* __restrict__ rnd,
    int* __restrict__ counts, float* __restrict__ quant,
    float* __restrict__ out_mi)
{
    const int wid  = threadIdx.x >> 6;
    const int lane = threadIdx.x & 63;
    const int row  = blockIdx.x * 4 + wid;
    const double x0 = X[(size_t)row * 128 + lane];
    const double x1 = X[(size_t)row * 128 + 64 + lane];
    double bestv = 1e300; int bestk = 0;
    for (int c = 0; c < 16; ++c) {
        int k = cand[(size_t)row * 16 + c] & (KCB - 1);   // defensive clamp
        double t0 = x0 - (double)cb[(size_t)k * 128 + lane];
        double t1 = x1 - (double)cb[(size_t)k * 128 + 64 + lane];
        double s = t0 * t0 + t1 * t1;
        #pragma unroll
        for (int off = 32; off > 0; off >>= 1) s += __shfl_xor(s, off, 64);
        if (s < bestv) { bestv = s; bestk = k; }
    }
    double r0 = (double)rnd[(size_t)row * 128 + lane];
    double r1 = (double)rnd[(size_t)row * 128 + 64 + lane];
    double rs = r0 * r0 + r1 * r1;
    #pragma unroll
    for (int off = 32; off > 0; off >>= 1) rs += __shfl_xor(rs, off, 64);
    double ratio = sqrt(bestv) / sqrt(rs) + 1e-12;
    quant[(size_t)row * 128 + lane]      = (float)(x0 + ratio * r0);
    quant[(size_t)row * 128 + 64 + lane] = (float)(x1 + ratio * r1);
    if (lane == 0) {
        out_mi[row] = (float)bestk;
        atomicAdd(counts + bestk, 1);
    }
}

// ---------------------------------------------------------------------------
// k_perplex: perplexity + new_used (single block)
__global__ __launch_bounds__(256) void k_perplex(
    const int* __restrict__ counts, const int* __restrict__ used_in,
    float* __restrict__ out_used, float* __restrict__ out_perp)
{
    __shared__ double red[256];
    int tid = threadIdx.x;
    double e = 0.0;
    for (int k = tid; k < KCB; k += 256) {
        int c = counts[k];
        out_used[k] = (float)(used_in[k] + c);
        if (c > 0) {
            double p = (double)c / 8192.0;
            e += p * log(p + 1e-12);
        }
    }
    red[tid] = e;
    __syncthreads();
    for (int s = 128; s > 0; s >>= 1) {
        if (tid < s) red[tid] += red[tid + s];
        __syncthreads();
    }
    if (tid == 0) out_perp[0] = (float)exp(-red[0]);
}

// ---------------------------------------------------------------------------
// k_decode: out[b,s2,m] = sum_d2 quant[b*8192 + d2*64 + s2] * W_out[d2,m] + b_out[m]
__global__ __launch_bounds__(256) void k_decode(
    const float* __restrict__ quant, const float* __restrict__ W_out,
    const float* __restrict__ b_out, float* __restrict__ out)
{
    __shared__ float As[8192];             // [d2][s2] (raw reinterpretation!)
    __shared__ float Bs[8192];             // [d2][64 m]
    const int tid = threadIdx.x;
    const int m0  = blockIdx.x * 64;
    const int b   = blockIdx.y;
    #pragma unroll
    for (int it = 0; it < 8; ++it) {
        int flat = it * 1024 + tid * 4;
        *(float4*)&As[flat] = *(const float4*)(quant + (size_t)b * 8192 + flat);
        int d2 = flat >> 6, m = flat & 63;
        *(float4*)&Bs[flat] = *(const float4*)(W_out + (size_t)d2 * 512 + m0 + m);
    }
    __syncthreads();
    const int tx = tid & 15, ty = tid >> 4;
    float acc[4][4];
    #pragma unroll
    for (int i = 0; i < 4; ++i)
        #pragma unroll
        for (int j = 0; j < 4; ++j) acc[i][j] = 0.f;
    #pragma unroll 8
    for (int d2 = 0; d2 < 128; ++d2) {
        float4 a  = *(const float4*)&As[d2 * 64 + ty * 4];
        float4 b4 = *(const float4*)&Bs[d2 * 64 + tx * 4];
        float av[4] = {a.x, a.y, a.z, a.w};
        float bv[4] = {b4.x, b4.y, b4.z, b4.w};
        #pragma unroll
        for (int i = 0; i < 4; ++i)
            #pragma unroll
            for (int j = 0; j < 4; ++j)
                acc[i][j] = fmaf(av[i], bv[j], acc[i][j]);
    }
    float4 bo = *(const float4*)(b_out + m0 + tx * 4);
    float bob[4] = {bo.x, bo.y, bo.z, bo.w};
    #pragma unroll
    for (int i = 0; i < 4; ++i) {
        int s2 = ty * 4 + i;
        float4 o;
        o.x = acc[i][0] + bob[0];
        o.y = acc[i][1] + bob[1];
        o.z = acc[i][2] + bob[2];
        o.w = acc[i][3] + bob[3];
        *(float4*)(out + (size_t)b * 32768 + (size_t)s2 * 512 + m0 + tx * 4) = o;
    }
}

// ---------------------------------------------------------------------------
extern "C" void kernel_launch(void* const* d_in, const int* in_sizes, int n_in,
                              void* d_out, int out_size, void* d_ws, size_t ws_size,
                              hipStream_t stream) {
    const float* first  = (const float*)d_in[0];
    const float* last   = (const float*)d_in[1];
    const float* rnd    = (const float*)d_in[2];
    const float* cb     = (const float*)d_in[3];
    const float* W_in   = (const float*)d_in[4];
    const float* conv_w = (const float*)d_in[6];
    const float* W_out  = (const float*)d_in[8];
    const float* b_out  = (const float*)d_in[9];
    const int*   used   = (const int*)d_in[10];

    float* out      = (float*)d_out;
    float* out_perp = out + 4194304;               // B*64*DIM
    float* out_used = out + 4194305;
    float* out_mi   = out + 4194305 + 16384;

    char* ws = (char*)d_ws;
    double*         H      = (double*)(ws);                 // 33,554,432 B
    double*         X      = (double*)(ws + 33554432);      //  8,388,608 B
    unsigned short* Cbb    = (unsigned short*)(ws + 41943040); // 4,194,304 B
    float*          W2     = (float*) (ws + 46137344);      //    589,824 B
    float*          c2f    = (float*) (ws + 46727168);      //     65,536 B
    int*            cand   = (int*)   (ws + 46792704);      //    524,288 B
    float*          quant  = (float*) (ws + 47316992);      //  4,194,304 B
    int*            counts = (int*)   (ws + 51511296);      //     65,536 B
    unsigned short* Xb     = (unsigned short*)(ws + 51576832); // 2,097,152 B
                                                            // total 53,673,984 B

    hipMemsetAsync(counts, 0, KCB * sizeof(int), stream);
    k_wt<<<576, 256, 0, stream>>>(conv_w, W2);
    k_c2<<<64, 256, 0, stream>>>(cb, c2f);
    k_cbbf<<<2048, 256, 0, stream>>>(cb, Cbb);
    k_encode_gemm<<<512, 256, 0, stream>>>(last, first, W_in, H);
    k_conv<<<1024, 256, 0, stream>>>(H, W2, X, Xb);
    k_dist_mfma<<<dim3(64, 8), 256, 0, stream>>>(Xb, Cbb, c2f, cand);
    k_refine<<<2048, 256, 0, stream>>>(X, cb, cand, rnd, counts, quant, out_mi);
    k_perplex<<<1, 256, 0, stream>>>(counts, used, out_used, out_perp);
    k_decode<<<dim3(8, 128), 256, 0, stream>>>(quant, W_out, b_out, out);
}

// Round 4
// 456.499 us; speedup vs baseline: 1.1964x; 1.1045x over previous
//
#include <hip/hip_runtime.h>
#include <math.h>

// Problem constants
//   B=128, S=256, DIM=512, D=128, K=16384, grid 16x16 -> conv out 8x8 -> N=B*64=8192
#define NROWS 8192
#define KCB   16384

using frag_ab = __attribute__((ext_vector_type(8))) short;   // 8 bf16 (4 VGPR)
using frag_cd = __attribute__((ext_vector_type(4))) float;   // 4 fp32 acc
using f32x4   = __attribute__((ext_vector_type(4))) float;
using f64x4   = __attribute__((ext_vector_type(4))) double;  // fp64 MFMA acc

__device__ inline unsigned short f2bf(float f) {             // RNE f32->bf16
    unsigned u = __float_as_uint(f);
    return (unsigned short)((u + 0x7FFFu + ((u >> 16) & 1u)) >> 16);
}

// Layout self-probe for v_mfma_f64_16x16x4 (HW-validated in round 3):
// decodes per-lane/slot (m,n) of the D fragment; returns ok.
__device__ inline int mfma_f64_probe(int pm[4], int pn[4], int kq) {
    f64x4 z; z[0] = 0.0; z[1] = 0.0; z[2] = 0.0; z[3] = 0.0;
    const double dl = (double)(threadIdx.x & 63);
    f64x4 d1 = __builtin_amdgcn_mfma_f64_16x16x4f64(dl, 1.0, z, 0, 0, 0);
    f64x4 d2 = __builtin_amdgcn_mfma_f64_16x16x4f64(1.0, dl, z, 0, 0, 0);
    const double pk = (double)(1 << (4 * kq));         // 16^kq
    f64x4 d3 = __builtin_amdgcn_mfma_f64_16x16x4f64(pk, dl, z, 0, 0, 0);
    int okl = 1;
    #pragma unroll
    for (int s = 0; s < 4; ++s) {
        double v1 = d1[s] - 96.0, v2 = d2[s] - 96.0;
        int i1 = (int)v1, i2 = (int)v2;
        okl &= (d1[s] == (double)(96 + i1)) & (i1 >= 0) & (i1 < 64) & ((i1 & 3) == 0);
        okl &= (d2[s] == (double)(96 + i2)) & (i2 >= 0) & (i2 < 64) & ((i2 & 3) == 0);
        pm[s] = i1 >> 2;
        pn[s] = i2 >> 2;
        okl &= (d3[s] == 4369.0 * (double)pn[s] + 205056.0);
    }
    return __all(okl);
}

// ---------------------------------------------------------------------------
// k_wt: transpose conv_w [co][ci][kh][kw] -> W2 [(kh*3+kw)][ci][co]  (f32)
__global__ __launch_bounds__(256) void k_wt(const float* __restrict__ cw,
                                            float* __restrict__ W2) {
    int gid = blockIdx.x * 256 + threadIdx.x;     // 147456 total
    if (gid >= 147456) return;
    int co = gid & 127;
    int ci = (gid >> 7) & 127;
    int kk = gid >> 14;                           // 0..8
    W2[gid] = cw[(size_t)co * 1152 + ci * 9 + kk];
}

// ---------------------------------------------------------------------------
// k_c2: c2f[k] = sum_d cb[k][d]^2 + 1024  (bias keeps k_dist scores positive
// so raw float bits are a monotone sort key; k_refine never reads c2f)
__global__ __launch_bounds__(256) void k_c2(const float* __restrict__ cb,
                                            float* __restrict__ c2f) {
    int k = blockIdx.x * 256 + threadIdx.x;
    const float* row = cb + (size_t)k * 128;
    double s = 0.0;
    #pragma unroll
    for (int d = 0; d < 128; d += 4) {
        float4 v = *(const float4*)(row + d);
        s += (double)v.x * v.x + (double)v.y * v.y
           + (double)v.z * v.z + (double)v.w * v.w;
    }
    c2f[k] = (float)s + 1024.0f;
}

// ---------------------------------------------------------------------------
// k_cbbf: convert codebook f32 -> bf16 rows [16384][128]
__global__ __launch_bounds__(256) void k_cbbf(const float* __restrict__ cb,
                                              unsigned short* __restrict__ Cbb) {
    int gid = blockIdx.x * 256 + threadIdx.x;     // x4 elements, 524288 total
    float4 v = ((const float4*)cb)[gid];
    ushort4 o;
    o.x = f2bf(v.x); o.y = f2bf(v.y); o.z = f2bf(v.z); o.w = f2bf(v.w);
    ((ushort4*)Cbb)[gid] = o;
}

// ---------------------------------------------------------------------------
// k_encode_gemm: H = (last - first) @ W_in, fp64 via v_mfma_f64_16x16x4.
// M=32768, N=128, K=512. Block = 4 waves, tile BM=64 x BN=128, BK=32,
// grid 512 (2 blocks/CU). Wave w: wm=(w&1)*32 (2 m-frags), wn=(w>>1)*64
// (4 n-frags) -> 8 f64x4 accs. Probe validated on HW in round 3.
__global__ __launch_bounds__(256) void k_encode_gemm(
    const float* __restrict__ last, const float* __restrict__ first,
    const float* __restrict__ W_in, double* __restrict__ H)
{
    __shared__ double As[32][66];    // [k][row] 16.5 KiB (pad 64->66)
    __shared__ double Bs[32][132];   // [k][col] 33.0 KiB (pad 128->132)
    const int tid  = threadIdx.x;
    const int lane = tid & 63;
    const int w    = tid >> 6;
    const int row0 = blockIdx.x * 64;
    const int wm   = (w & 1) * 32;
    const int wn   = (w >> 1) * 64;
    const int lm   = lane & 15;
    const int kq   = lane >> 4;

    int pm[4], pn[4];
    const int ok = mfma_f64_probe(pm, pn, kq);
    if (!ok) {
        #pragma unroll
        for (int s = 0; s < 4; ++s) { pm[s] = 4 * kq + s; pn[s] = lm; }
    }

    f64x4 acc[2][4];
    #pragma unroll
    for (int i = 0; i < 2; ++i)
        #pragma unroll
        for (int j = 0; j < 4; ++j)
            #pragma unroll
            for (int q = 0; q < 4; ++q) acc[i][j][q] = 0.0;

    const int ar = tid >> 2;             // A-stage: row 0..63
    const int ak = (tid & 3) * 8;        // A-stage: k base 0,8,16,24
    const int bkk = tid >> 3;            // B-stage: k 0..31
    const int bc  = (tid & 7) * 16;      // B-stage: col base 0..112

    for (int k0 = 0; k0 < 512; k0 += 32) {
        if (k0) __syncthreads();
        {   // stage A-diff (f64, transposed): 64 rows x 32 k
            const float* lp = last  + (size_t)(row0 + ar) * 512 + k0 + ak;
            const float* fp = first + (size_t)(row0 + ar) * 512 + k0 + ak;
            const float4 l0 = *(const float4*)(lp);
            const float4 l1 = *(const float4*)(lp + 4);
            const float4 f0 = *(const float4*)(fp);
            const float4 f1 = *(const float4*)(fp + 4);
            As[ak + 0][ar] = (double)l0.x - (double)f0.x;
            As[ak + 1][ar] = (double)l0.y - (double)f0.y;
            As[ak + 2][ar] = (double)l0.z - (double)f0.z;
            As[ak + 3][ar] = (double)l0.w - (double)f0.w;
            As[ak + 4][ar] = (double)l1.x - (double)f1.x;
            As[ak + 5][ar] = (double)l1.y - (double)f1.y;
            As[ak + 6][ar] = (double)l1.z - (double)f1.z;
            As[ak + 7][ar] = (double)l1.w - (double)f1.w;
        }
        {   // stage B (f64): 32 k x 128 cols
            const float* wp = W_in + (size_t)(k0 + bkk) * 128 + bc;
            #pragma unroll
            for (int q = 0; q < 4; ++q) {
                const float4 b4 = *(const float4*)(wp + 4 * q);
                Bs[bkk][bc + 4 * q + 0] = (double)b4.x;
                Bs[bkk][bc + 4 * q + 1] = (double)b4.y;
                Bs[bkk][bc + 4 * q + 2] = (double)b4.z;
                Bs[bkk][bc + 4 * q + 3] = (double)b4.w;
            }
        }
        __syncthreads();
        if (ok) {
            #pragma unroll
            for (int kc = 0; kc < 8; ++kc) {
                const int kk = kc * 4 + kq;
                double a0 = As[kk][wm + lm];
                double a1 = As[kk][wm + 16 + lm];
                double b0 = Bs[kk][wn + lm];
                double b1 = Bs[kk][wn + 16 + lm];
                double b2 = Bs[kk][wn + 32 + lm];
                double b3 = Bs[kk][wn + 48 + lm];
                acc[0][0] = __builtin_amdgcn_mfma_f64_16x16x4f64(a0, b0, acc[0][0], 0, 0, 0);
                acc[0][1] = __builtin_amdgcn_mfma_f64_16x16x4f64(a0, b1, acc[0][1], 0, 0, 0);
                acc[0][2] = __builtin_amdgcn_mfma_f64_16x16x4f64(a0, b2, acc[0][2], 0, 0, 0);
                acc[0][3] = __builtin_amdgcn_mfma_f64_16x16x4f64(a0, b3, acc[0][3], 0, 0, 0);
                acc[1][0] = __builtin_amdgcn_mfma_f64_16x16x4f64(a1, b0, acc[1][0], 0, 0, 0);
                acc[1][1] = __builtin_amdgcn_mfma_f64_16x16x4f64(a1, b1, acc[1][1], 0, 0, 0);
                acc[1][2] = __builtin_amdgcn_mfma_f64_16x16x4f64(a1, b2, acc[1][2], 0, 0, 0);
                acc[1][3] = __builtin_amdgcn_mfma_f64_16x16x4f64(a1, b3, acc[1][3], 0, 0, 0);
            }
        } else {
            #pragma unroll 4
            for (int k = 0; k < 32; ++k) {
                double b0 = Bs[k][wn + lm];
                double b1 = Bs[k][wn + 16 + lm];
                double b2 = Bs[k][wn + 32 + lm];
                double b3 = Bs[k][wn + 48 + lm];
                #pragma unroll
                for (int i = 0; i < 2; ++i) {
                    const double* ap = &As[k][wm + i * 16 + 4 * kq];
                    #pragma unroll
                    for (int s = 0; s < 4; ++s) {
                        double a = ap[s];
                        acc[i][0][s] = fma(a, b0, acc[i][0][s]);
                        acc[i][1][s] = fma(a, b1, acc[i][1][s]);
                        acc[i][2][s] = fma(a, b2, acc[i][2][s]);
                        acc[i][3][s] = fma(a, b3, acc[i][3][s]);
                    }
                }
            }
        }
    }
    #pragma unroll
    for (int i = 0; i < 2; ++i)
        #pragma unroll
        for (int j = 0; j < 4; ++j)
            #pragma unroll
            for (int s = 0; s < 4; ++s)
                H[(size_t)(row0 + wm + i * 16 + pm[s]) * 128 + wn + j * 16 + pn[s]]
                    = acc[i][j][s];
}

// ---------------------------------------------------------------------------
// k_conv: 3x3 stride-2 pad-1 conv (no bias; cancels), fp64 via MFMA.
// im2col GEMM: M=8192 out rows, N=128 co, K=9 taps x 128 ci.
// Block = 16 rows (batch b, oh pair {2j,2j+1}); input slice ih in
// [4j-1, 4j+3] -> Hs[5][16][128] f64 = 80 KiB exactly -> 2 blocks/CU.
// 4 waves x 32 co: per wave 1 m-frag x 2 n-frags; A from LDS (OOB taps
// masked by 0/1 multiplier), B = W2 f32 direct from L1/L2 + cvt.
// K-order tap-major (reassociation vs ci-major baseline: fp64 ulp, safe).
// Same probe + scalar fallback as encode.
__global__ __launch_bounds__(256) void k_conv(
    const double* __restrict__ H, const float* __restrict__ W2,
    double* __restrict__ X, unsigned short* __restrict__ Xb)
{
    __shared__ double Hs[5 * 2048];          // [ihr][iw][ci]  80 KiB exact
    const int tid  = threadIdx.x;
    const int lane = tid & 63;
    const int w    = tid >> 6;
    const int n0   = blockIdx.x * 16;        // 16 output rows
    const int b    = blockIdx.x >> 2;
    const int j    = blockIdx.x & 3;         // oh in {2j, 2j+1}
    const int ihbase = 4 * j - 1;
    const int wn   = w * 32;
    const int lm   = lane & 15;
    const int kq   = lane >> 4;

    int pm[4], pn[4];
    const int ok = mfma_f64_probe(pm, pn, kq);

    // stage 5 H rows (zero-fill ih=-1 for j==0)
    #pragma unroll
    for (int it = 0; it < 20; ++it) {
        int slot = it * 256 + tid;           // 5120 double2 slots
        int r = slot >> 10;                  // 0..4
        int rem = (slot & 1023) * 2;         // f64 offset within row
        int ih = ihbase + r;
        double2 v = (ih >= 0)
            ? *(const double2*)(H + (size_t)b * 32768 + (size_t)ih * 2048 + rem)
            : make_double2(0.0, 0.0);
        *(double2*)&Hs[r * 2048 + rem] = v;
    }
    __syncthreads();

    if (ok) {
        f64x4 acc0, acc1;
        #pragma unroll
        for (int q = 0; q < 4; ++q) { acc0[q] = 0.0; acc1[q] = 0.0; }
        const int ow = lm & 7, ohl = lm >> 3;
        #pragma unroll
        for (int kh = 0; kh < 3; ++kh) {
            #pragma unroll
            for (int kw = 0; kw < 3; ++kw) {
                const int tap = kh * 3 + kw;
                const int iw  = 2 * ow - 1 + kw;
                const int ihr = 2 * ohl + kh;
                const int valid = (iw >= 0) & (ihbase + ihr >= 0);
                const int aoff = valid ? (ihr * 2048 + iw * 128 + kq) : 0;
                const double msk = valid ? 1.0 : 0.0;
                const float* wbase = W2 + (size_t)(tap * 128 + kq) * 128 + wn + lm;
                #pragma unroll 4
                for (int ci0 = 0; ci0 < 128; ci0 += 4) {
                    double a  = Hs[aoff + ci0] * msk;
                    double b0 = (double)wbase[ci0 * 128];
                    double b1 = (double)wbase[ci0 * 128 + 16];
                    acc0 = __builtin_amdgcn_mfma_f64_16x16x4f64(a, b0, acc0, 0, 0, 0);
                    acc1 = __builtin_amdgcn_mfma_f64_16x16x4f64(a, b1, acc1, 0, 0, 0);
                }
            }
        }
        #pragma unroll
        for (int s = 0; s < 4; ++s) {
            size_t n = n0 + pm[s];
            int c0 = wn + pn[s];
            X [n * 128 + c0]      = acc0[s];
            Xb[n * 128 + c0]      = f2bf((float)acc0[s]);
            X [n * 128 + c0 + 16] = acc1[s];
            Xb[n * 128 + c0 + 16] = f2bf((float)acc1[s]);
        }
    } else {
        // scalar fallback (never runs on validated HW): 8 outputs/thread
        const int co   = wn + (lane & 31);
        const int half = lane >> 5;
        double facc[8];
        #pragma unroll
        for (int i = 0; i < 8; ++i) facc[i] = 0.0;
        for (int ci = 0; ci < 128; ++ci) {
            #pragma unroll
            for (int kh = 0; kh < 3; ++kh) {
                #pragma unroll
                for (int kw = 0; kw < 3; ++kw) {
                    double wv = (double)W2[(size_t)((kh * 3 + kw) * 128 + ci) * 128 + co];
                    #pragma unroll
                    for (int i = 0; i < 8; ++i) {
                        int m = half * 8 + i;
                        int iw = 2 * (m & 7) - 1 + kw;
                        int ihr = 2 * (m >> 3) + kh;
                        double hv = (iw >= 0 && ihbase + ihr >= 0)
                                  ? Hs[ihr * 2048 + iw * 128 + ci] : 0.0;
                        facc[i] = fma(hv, wv, facc[i]);
                    }
                }
            }
        }
        #pragma unroll
        for (int i = 0; i < 8; ++i) {
            size_t n = n0 + half * 8 + i;
            X [n * 128 + co] = facc[i];
            Xb[n * 128 + co] = f2bf((float)facc[i]);
        }
    }
}

// ---------------------------------------------------------------------------
// k_dist_mfma: bf16 MFMA candidate sweep. Block = 128 rows x 2048-code split;
// grid (64, 8) = 512 blocks (2/CU). Per chunk of 128 codes: 16x16x32 MFMA,
// codes as M, rows as N (D: col=lane&15=row, row=quad*4+reg=code).
// LDS exactly 64 KiB; 16B chunks XOR-swizzled (ch ^= row&15) -> conflict-free.
// Selection: score u = (||c||^2+1024) - 2 x.c > 0; sortable uint key =
// (bits(u) & ~0x7FF) | split-local code idx (11 bits); top-2 per (lane,row)
// class via min/max (no cndmask), then per-row top-2 of 16 via LDS.
// Coverage: bf16 noise sigma~0.05 + trunc <0.5 vs rank gaps ~7-20 -> safe;
// fp64 k_refine picks the exact argmin among the 16 candidates.
__global__ __launch_bounds__(256) void k_dist_mfma(
    const unsigned short* __restrict__ Xb, const unsigned short* __restrict__ Cbb,
    const float* __restrict__ c2f, int* __restrict__ cand)
{
    __shared__ __align__(16) unsigned short Xs[128 * 128];   // 32 KiB
    __shared__ __align__(16) unsigned short Cs[128 * 128];   // 32 KiB
    const int tid   = threadIdx.x;
    const int row0  = blockIdx.x * 128;
    const int split = blockIdx.y;
    const int lane  = tid & 63;
    const int w     = tid >> 6;
    const int quad  = lane >> 4;
    const int lm    = lane & 15;
    const int cw    = (w & 1) * 64;       // wave's code sub-tile
    const int rw    = (w >> 1) * 64;      // wave's row sub-tile

    #pragma unroll
    for (int it = 0; it < 8; ++it) {      // stage X tile once (swizzled)
        int flat = it * 256 + tid;
        int r = flat >> 4, ch = flat & 15;
        *(uint4*)&Xs[r * 128 + (((ch ^ r) & 15) << 3) + (ch & 16 ? 0 : 0)] =
            *(const uint4*)(Xb + (size_t)(row0 + r) * 128 + ch * 8);
    }

    unsigned k1[4], k2[4];
    #pragma unroll
    for (int j = 0; j < 4; ++j) { k1[j] = 0xFFFFFFFFu; k2[j] = 0xFFFFFFFFu; }

    for (int chunk = 0; chunk < 16; ++chunk) {
        const int kb = split * 2048 + chunk * 128;
        if (chunk) __syncthreads();
        #pragma unroll
        for (int it = 0; it < 8; ++it) {  // stage code chunk (swizzled)
            int flat = it * 256 + tid;
            int r = flat >> 4, ch = flat & 15;
            *(uint4*)&Cs[r * 128 + ((ch ^ (r & 15)) << 3)] =
                *(const uint4*)(Cbb + (size_t)(kb + r) * 128 + ch * 8);
        }
        __syncthreads();

        frag_cd acc[4][4];
        #pragma unroll
        for (int i = 0; i < 4; ++i)
            #pragma unroll
            for (int j = 0; j < 4; ++j)
                #pragma unroll
                for (int r = 0; r < 4; ++r) acc[i][j][r] = 0.f;

        #pragma unroll
        for (int kk = 0; kk < 4; ++kk) {
            const int chs = ((kk * 4 + quad) ^ lm) << 3;
            frag_ab a[4], b[4];
            #pragma unroll
            for (int i = 0; i < 4; ++i)
                a[i] = *(const frag_ab*)&Cs[(cw + i * 16 + lm) * 128 + chs];
            #pragma unroll
            for (int j = 0; j < 4; ++j)
                b[j] = *(const frag_ab*)&Xs[(rw + j * 16 + lm) * 128 + chs];
            #pragma unroll
            for (int i = 0; i < 4; ++i)
                #pragma unroll
                for (int j = 0; j < 4; ++j)
                    acc[i][j] = __builtin_amdgcn_mfma_f32_16x16x32_bf16(
                        a[i], b[j], acc[i][j], 0, 0, 0);
        }

        const int ib = chunk * 128 + cw + quad * 4;   // split-local idx base
        #pragma unroll
        for (int i = 0; i < 4; ++i) {
            f32x4 c2v = *(const f32x4*)(c2f + kb + cw + i * 16 + quad * 4);
            #pragma unroll
            for (int j = 0; j < 4; ++j) {
                #pragma unroll
                for (int r = 0; r < 4; ++r) {
                    float u = fmaf(-2.f, acc[i][j][r], c2v[r]);
                    unsigned key = (__float_as_uint(u) & 0xFFFFF800u)
                                 | (unsigned)(ib + i * 16 + r);
                    unsigned nk1 = min(key, k1[j]);
                    k2[j] = min(max(key, k1[j]), k2[j]);
                    k1[j] = nk1;
                }
            }
        }
    }

    // per-row reduce: 8 slots x 2 keys -> top-2 of the split
    __syncthreads();
    uint2* kred = (uint2*)Cs;             // [128 rows][8 slots]
    #pragma unroll
    for (int j = 0; j < 4; ++j)
        kred[(rw + j * 16 + lm) * 8 + (w & 1) * 4 + quad] = make_uint2(k1[j], k2[j]);
    __syncthreads();
    if (tid < 128) {
        unsigned b1 = 0xFFFFFFFFu, b2 = 0xFFFFFFFFu;
        for (int e = 0; e < 8; ++e) {
            uint2 kv = kred[tid * 8 + e];
            unsigned n1 = min(kv.x, b1); b2 = min(max(kv.x, b1), b2); b1 = n1;
            n1 = min(kv.y, b1);          b2 = min(max(kv.y, b1), b2); b1 = n1;
        }
        int base = split * 2048;
        int* o = cand + (size_t)(row0 + tid) * 16 + split * 2;
        o[0] = base + (int)(b1 & 0x7FFu);
        o[1] = base + (int)(b2 & 0x7FFu);
    }
}

// ---------------------------------------------------------------------------
// k_refine: fp64-exact argmin over 16 candidates; quantize; counts; indices.
__global__ __launch_bounds__(256) void k_refine(
    const double* __restrict__ X, const float* __restrict__ cb,
    const int* __restrict__ cand, const float* __restrict__ rnd,
    int* __restrict__ counts, float* __restrict__ quant,
    float* __restrict__ out_mi)
{
    const int wid  = threadIdx.x >> 6;
    const int lane = threadIdx.x & 63;
    const int row  = blockIdx.x * 4 + wid;
    const double x0 = X[(size_t)row * 128 + lane];
    const double x1 = X[(size_t)row * 128 + 64 + lane];
    double bestv = 1e300; int bestk = 0;
    for (int c = 0; c < 16; ++c) {
        int k = cand[(size_t)row * 16 + c] & (KCB - 1);   // defensive clamp
        double t0 = x0 - (double)cb[(size_t)k * 128 + lane];
        double t1 = x1 - (double)cb[(size_t)k * 128 + 64 + lane];
        double s = t0 * t0 + t1 * t1;
        #pragma unroll
        for (int off = 32; off > 0; off >>= 1) s += __shfl_xor(s, off, 64);
        if (s < bestv) { bestv = s; bestk = k; }
    }
    double r0 = (double)rnd[(size_t)row * 128 + lane];
    double r1 = (double)rnd[(size_t)row * 128 + 64 + lane];
    double rs = r0 * r0 + r1 * r1;
    #pragma unroll
    for (int off = 32; off > 0; off >>= 1) rs += __shfl_xor(rs, off, 64);
    double ratio = sqrt(bestv) / sqrt(rs) + 1e-12;
    quant[(size_t)row * 128 + lane]      = (float)(x0 + ratio * r0);
    quant[(size_t)row * 128 + 64 + lane] = (float)(x1 + ratio * r1);
    if (lane == 0) {
        out_mi[row] = (float)bestk;
        atomicAdd(counts + bestk, 1);
    }
}

// ---------------------------------------------------------------------------
// k_perplex: perplexity + new_used (single block)
__global__ __launch_bounds__(256) void k_perplex(
    const int* __restrict__ counts, const int* __restrict__ used_in,
    float* __restrict__ out_used, float* __restrict__ out_perp)
{
    __shared__ double red[256];
    int tid = threadIdx.x;
    double e = 0.0;
    for (int k = tid; k < KCB; k += 256) {
        int c = counts[k];
        out_used[k] = (float)(used_in[k] + c);
        if (c > 0) {
            double p = (double)c / 8192.0;
            e += p * log(p + 1e-12);
        }
    }
    red[tid] = e;
    __syncthreads();
    for (int s = 128; s > 0; s >>= 1) {
        if (tid < s) red[tid] += red[tid + s];
        __syncthreads();
    }
    if (tid == 0) out_perp[0] = (float)exp(-red[0]);
}

// ---------------------------------------------------------------------------
// k_decode: out[b,s2,m] = sum_d2 quant[b*8192 + d2*64 + s2] * W_out[d2,m] + b_out[m]
__global__ __launch_bounds__(256) void k_decode(
    const float* __restrict__ quant, const float* __restrict__ W_out,
    const float* __restrict__ b_out, float* __restrict__ out)
{
    __shared__ float As[8192];             // [d2][s2] (raw reinterpretation!)
    __shared__ float Bs[8192];             // [d2][64 m]
    const int tid = threadIdx.x;
    const int m0  = blockIdx.x * 64;
    const int b   = blockIdx.y;
    #pragma unroll
    for (int it = 0; it < 8; ++it) {
        int flat = it * 1024 + tid * 4;
        *(float4*)&As[flat] = *(const float4*)(quant + (size_t)b * 8192 + flat);
        int d2 = flat >> 6, m = flat & 63;
        *(float4*)&Bs[flat] = *(const float4*)(W_out + (size_t)d2 * 512 + m0 + m);
    }
    __syncthreads();
    const int tx = tid & 15, ty = tid >> 4;
    float acc[4][4];
    #pragma unroll
    for (int i = 0; i < 4; ++i)
        #pragma unroll
        for (int j = 0; j < 4; ++j) acc[i][j] = 0.f;
    #pragma unroll 8
    for (int d2 = 0; d2 < 128; ++d2) {
        float4 a  = *(const float4*)&As[d2 * 64 + ty * 4];
        float4 b4 = *(const float4*)&Bs[d2 * 64 + tx * 4];
        float av[4] = {a.x, a.y, a.z, a.w};
        float bv[4] = {b4.x, b4.y, b4.z, b4.w};
        #pragma unroll
        for (int i = 0; i < 4; ++i)
            #pragma unroll
            for (int j = 0; j < 4; ++j)
                acc[i][j] = fmaf(av[i], bv[j], acc[i][j]);
    }
    float4 bo = *(const float4*)(b_out + m0 + tx * 4);
    float bob[4] = {bo.x, bo.y, bo.z, bo.w};
    #pragma unroll
    for (int i = 0; i < 4; ++i) {
        int s2 = ty * 4 + i;
        float4 o;
        o.x = acc[i][0] + bob[0];
        o.y = acc[i][1] + bob[1];
        o.z = acc[i][2] + bob[2];
        o.w = acc[i][3] + bob[3];
        *(float4*)(out + (size_t)b * 32768 + (size_t)s2 * 512 + m0 + tx * 4) = o;
    }
}

// ---------------------------------------------------------------------------
extern "C" void kernel_launch(void* const* d_in, const int* in_sizes, int n_in,
                              void* d_out, int out_size, void* d_ws, size_t ws_size,
                              hipStream_t stream) {
    const float* first  = (const float*)d_in[0];
    const float* last   = (const float*)d_in[1];
    const float* rnd    = (const float*)d_in[2];
    const float* cb     = (const float*)d_in[3];
    const float* W_in   = (const float*)d_in[4];
    const float* conv_w = (const float*)d_in[6];
    const float* W_out  = (const float*)d_in[8];
    const float* b_out  = (const float*)d_in[9];
    const int*   used   = (const int*)d_in[10];

    float* out      = (float*)d_out;
    float* out_perp = out + 4194304;               // B*64*DIM
    float* out_used = out + 4194305;
    float* out_mi   = out + 4194305 + 16384;

    char* ws = (char*)d_ws;
    double*         H      = (double*)(ws);                 // 33,554,432 B
    double*         X      = (double*)(ws + 33554432);      //  8,388,608 B
    unsigned short* Cbb    = (unsigned short*)(ws + 41943040); // 4,194,304 B
    float*          W2     = (float*) (ws + 46137344);      //    589,824 B
    float*          c2f    = (float*) (ws + 46727168);      //     65,536 B
    int*            cand   = (int*)   (ws + 46792704);      //    524,288 B
    float*          quant  = (float*) (ws + 47316992);      //  4,194,304 B
    int*            counts = (int*)   (ws + 51511296);      //     65,536 B
    unsigned short* Xb     = (unsigned short*)(ws + 51576832); // 2,097,152 B
                                                            // total 53,673,984 B

    hipMemsetAsync(counts, 0, KCB * sizeof(int), stream);
    k_wt<<<576, 256, 0, stream>>>(conv_w, W2);
    k_c2<<<64, 256, 0, stream>>>(cb, c2f);
    k_cbbf<<<2048, 256, 0, stream>>>(cb, Cbb);
    k_encode_gemm<<<512, 256, 0, stream>>>(last, first, W_in, H);
    k_conv<<<512, 256, 0, stream>>>(H, W2, X, Xb);
    k_dist_mfma<<<dim3(64, 8), 256, 0, stream>>>(Xb, Cbb, c2f, cand);
    k_refine<<<2048, 256, 0, stream>>>(X, cb, cand, rnd, counts, quant, out_mi);
    k_perplex<<<1, 256, 0, stream>>>(counts, used, out_used, out_perp);
    k_decode<<<dim3(8, 128), 256, 0, stream>>>(quant, W_out, b_out, out);
}

// Round 5
// 432.909 us; speedup vs baseline: 1.2616x; 1.0545x over previous
//
#include <hip/hip_runtime.h>
#include <math.h>

// Problem constants
//   B=128, S=256, DIM=512, D=128, K=16384, grid 16x16 -> conv out 8x8 -> N=B*64=8192
#define NROWS 8192
#define KCB   16384

using frag_ab = __attribute__((ext_vector_type(8))) short;   // 8 bf16 (4 VGPR)
using frag_cd = __attribute__((ext_vector_type(4))) float;   // 4 fp32 acc
using f32x4   = __attribute__((ext_vector_type(4))) float;
using f64x4   = __attribute__((ext_vector_type(4))) double;  // fp64 MFMA acc

__device__ inline unsigned short f2bf(float f) {             // RNE f32->bf16
    unsigned u = __float_as_uint(f);
    return (unsigned short)((u + 0x7FFFu + ((u >> 16) & 1u)) >> 16);
}

// Layout self-probe for v_mfma_f64_16x16x4 (HW-validated in round 3):
// decodes per-lane/slot (m,n) of the D fragment; returns ok.
__device__ inline int mfma_f64_probe(int pm[4], int pn[4], int kq) {
    f64x4 z; z[0] = 0.0; z[1] = 0.0; z[2] = 0.0; z[3] = 0.0;
    const double dl = (double)(threadIdx.x & 63);
    f64x4 d1 = __builtin_amdgcn_mfma_f64_16x16x4f64(dl, 1.0, z, 0, 0, 0);
    f64x4 d2 = __builtin_amdgcn_mfma_f64_16x16x4f64(1.0, dl, z, 0, 0, 0);
    const double pk = (double)(1 << (4 * kq));         // 16^kq
    f64x4 d3 = __builtin_amdgcn_mfma_f64_16x16x4f64(pk, dl, z, 0, 0, 0);
    int okl = 1;
    #pragma unroll
    for (int s = 0; s < 4; ++s) {
        double v1 = d1[s] - 96.0, v2 = d2[s] - 96.0;
        int i1 = (int)v1, i2 = (int)v2;
        okl &= (d1[s] == (double)(96 + i1)) & (i1 >= 0) & (i1 < 64) & ((i1 & 3) == 0);
        okl &= (d2[s] == (double)(96 + i2)) & (i2 >= 0) & (i2 < 64) & ((i2 & 3) == 0);
        pm[s] = i1 >> 2;
        pn[s] = i2 >> 2;
        okl &= (d3[s] == 4369.0 * (double)pn[s] + 205056.0);
    }
    return __all(okl);
}

// ---------------------------------------------------------------------------
// k_wt: transpose conv_w [co][ci][kh][kw] -> W2 [(kh*3+kw)][ci][co]  (f32)
__global__ __launch_bounds__(256) void k_wt(const float* __restrict__ cw,
                                            float* __restrict__ W2) {
    int gid = blockIdx.x * 256 + threadIdx.x;     // 147456 total
    if (gid >= 147456) return;
    int co = gid & 127;
    int ci = (gid >> 7) & 127;
    int kk = gid >> 14;                           // 0..8
    W2[gid] = cw[(size_t)co * 1152 + ci * 9 + kk];
}

// ---------------------------------------------------------------------------
// k_c2: c2f[k] = sum_d cb[k][d]^2 + 1024  (bias keeps k_dist scores positive
// so raw float bits are a monotone sort key; k_refine never reads c2f)
__global__ __launch_bounds__(256) void k_c2(const float* __restrict__ cb,
                                            float* __restrict__ c2f) {
    int k = blockIdx.x * 256 + threadIdx.x;
    const float* row = cb + (size_t)k * 128;
    double s = 0.0;
    #pragma unroll
    for (int d = 0; d < 128; d += 4) {
        float4 v = *(const float4*)(row + d);
        s += (double)v.x * v.x + (double)v.y * v.y
           + (double)v.z * v.z + (double)v.w * v.w;
    }
    c2f[k] = (float)s + 1024.0f;
}

// ---------------------------------------------------------------------------
// k_cbbf: convert codebook f32 -> bf16 rows [16384][128]
__global__ __launch_bounds__(256) void k_cbbf(const float* __restrict__ cb,
                                              unsigned short* __restrict__ Cbb) {
    int gid = blockIdx.x * 256 + threadIdx.x;     // x4 elements, 524288 total
    float4 v = ((const float4*)cb)[gid];
    ushort4 o;
    o.x = f2bf(v.x); o.y = f2bf(v.y); o.z = f2bf(v.z); o.w = f2bf(v.w);
    ((ushort4*)Cbb)[gid] = o;
}

// ---------------------------------------------------------------------------
// k_encode_gemm: H = (last - first) @ W_in, fp64 via v_mfma_f64_16x16x4.
// M=32768, N=128, K=512. Round-5 restructure (k_conv recipe):
//  - B NOT staged in LDS: read W_in f32 direct from L1/L2 + cvt in the MFMA
//    loop (256 KB, chip-resident, shared by all blocks). Kills the 8-way
//    Bs-staging bank conflicts (17.8M cy in round 4) and halves barrier work.
//  - BM=32, BK=64, grid 1024 -> 4 blocks/CU, 16 waves/CU (was 2 blocks/CU,
//    grid-capped 20.5% occupancy). 4 independent-barrier blocks per CU
//    overlap each other's staging drains.
//  - Wave w: all 32 rows x cols [w*32, w*32+32) -> 2x2 f64x4 accs.
// MFMA k-quad sequence identical to the round-4 proven path (k ascending,
// quads of 4) -> bit-identical H. Same probe + scalar fallback.
__global__ __launch_bounds__(256, 4) void k_encode_gemm(
    const float* __restrict__ last, const float* __restrict__ first,
    const float* __restrict__ W_in, double* __restrict__ H)
{
    __shared__ double As[64][33];    // [k][row] 16.9 KiB (pad 32->33)
    const int tid  = threadIdx.x;
    const int lane = tid & 63;
    const int w    = tid >> 6;
    const int row0 = blockIdx.x * 32;
    const int wn   = w * 32;
    const int lm   = lane & 15;
    const int kq   = lane >> 4;

    int pm[4], pn[4];
    const int ok = mfma_f64_probe(pm, pn, kq);
    if (!ok) {
        #pragma unroll
        for (int s = 0; s < 4; ++s) { pm[s] = 4 * kq + s; pn[s] = lm; }
    }

    f64x4 acc[2][2];
    #pragma unroll
    for (int i = 0; i < 2; ++i)
        #pragma unroll
        for (int j = 0; j < 2; ++j)
            #pragma unroll
            for (int q = 0; q < 4; ++q) acc[i][j][q] = 0.0;

    const int srow = tid >> 3;           // A-stage: row 0..31
    const int skb  = (tid & 7) * 8;      // A-stage: k base 0,8,...,56

    for (int k0 = 0; k0 < 512; k0 += 64) {
        if (k0) __syncthreads();
        {   // stage A-diff (f64, transposed): 32 rows x 64 k
            const float* lp = last  + (size_t)(row0 + srow) * 512 + k0 + skb;
            const float* fp = first + (size_t)(row0 + srow) * 512 + k0 + skb;
            const float4 l0 = *(const float4*)(lp);
            const float4 l1 = *(const float4*)(lp + 4);
            const float4 f0 = *(const float4*)(fp);
            const float4 f1 = *(const float4*)(fp + 4);
            As[skb + 0][srow] = (double)l0.x - (double)f0.x;
            As[skb + 1][srow] = (double)l0.y - (double)f0.y;
            As[skb + 2][srow] = (double)l0.z - (double)f0.z;
            As[skb + 3][srow] = (double)l0.w - (double)f0.w;
            As[skb + 4][srow] = (double)l1.x - (double)f1.x;
            As[skb + 5][srow] = (double)l1.y - (double)f1.y;
            As[skb + 6][srow] = (double)l1.z - (double)f1.z;
            As[skb + 7][srow] = (double)l1.w - (double)f1.w;
        }
        __syncthreads();
        if (ok) {
            #pragma unroll
            for (int kc = 0; kc < 16; ++kc) {
                const int kk = kc * 4 + kq;
                const float* wb = W_in + (size_t)(k0 + kk) * 128 + wn + lm;
                double a0 = As[kk][lm];
                double a1 = As[kk][16 + lm];
                double b0 = (double)wb[0];
                double b1 = (double)wb[16];
                acc[0][0] = __builtin_amdgcn_mfma_f64_16x16x4f64(a0, b0, acc[0][0], 0, 0, 0);
                acc[0][1] = __builtin_amdgcn_mfma_f64_16x16x4f64(a0, b1, acc[0][1], 0, 0, 0);
                acc[1][0] = __builtin_amdgcn_mfma_f64_16x16x4f64(a1, b0, acc[1][0], 0, 0, 0);
                acc[1][1] = __builtin_amdgcn_mfma_f64_16x16x4f64(a1, b1, acc[1][1], 0, 0, 0);
            }
        } else {
            #pragma unroll 4
            for (int k = 0; k < 64; ++k) {
                double b0 = (double)W_in[(size_t)(k0 + k) * 128 + wn + lm];
                double b1 = (double)W_in[(size_t)(k0 + k) * 128 + wn + 16 + lm];
                #pragma unroll
                for (int i = 0; i < 2; ++i) {
                    const double* ap = &As[k][16 * i + 4 * kq];
                    #pragma unroll
                    for (int s = 0; s < 4; ++s) {
                        double a = ap[s];
                        acc[i][0][s] = fma(a, b0, acc[i][0][s]);
                        acc[i][1][s] = fma(a, b1, acc[i][1][s]);
                    }
                }
            }
        }
    }
    #pragma unroll
    for (int i = 0; i < 2; ++i)
        #pragma unroll
        for (int j = 0; j < 2; ++j)
            #pragma unroll
            for (int s = 0; s < 4; ++s)
                H[(size_t)(row0 + 16 * i + pm[s]) * 128 + wn + 16 * j + pn[s]]
                    = acc[i][j][s];
}

// ---------------------------------------------------------------------------
// k_conv: 3x3 stride-2 pad-1 conv (no bias; cancels), fp64 via MFMA.
// im2col GEMM: M=8192 out rows, N=128 co, K=9 taps x 128 ci.
// Block = 16 rows (batch b, oh pair {2j,2j+1}); input slice ih in
// [4j-1, 4j+3] -> Hs[5][16][128] f64 = 80 KiB exactly -> 2 blocks/CU.
// 4 waves x 32 co: per wave 1 m-frag x 2 n-frags; A from LDS (OOB taps
// masked by 0/1 multiplier), B = W2 f32 direct from L1/L2 + cvt.
// K-order tap-major (reassociation vs ci-major baseline: fp64 ulp, safe).
// Same probe + scalar fallback as encode.
__global__ __launch_bounds__(256) void k_conv(
    const double* __restrict__ H, const float* __restrict__ W2,
    double* __restrict__ X, unsigned short* __restrict__ Xb)
{
    __shared__ double Hs[5 * 2048];          // [ihr][iw][ci]  80 KiB exact
    const int tid  = threadIdx.x;
    const int lane = tid & 63;
    const int w    = tid >> 6;
    const int n0   = blockIdx.x * 16;        // 16 output rows
    const int b    = blockIdx.x >> 2;
    const int j    = blockIdx.x & 3;         // oh in {2j, 2j+1}
    const int ihbase = 4 * j - 1;
    const int wn   = w * 32;
    const int lm   = lane & 15;
    const int kq   = lane >> 4;

    int pm[4], pn[4];
    const int ok = mfma_f64_probe(pm, pn, kq);

    // stage 5 H rows (zero-fill ih=-1 for j==0)
    #pragma unroll
    for (int it = 0; it < 20; ++it) {
        int slot = it * 256 + tid;           // 5120 double2 slots
        int r = slot >> 10;                  // 0..4
        int rem = (slot & 1023) * 2;         // f64 offset within row
        int ih = ihbase + r;
        double2 v = (ih >= 0)
            ? *(const double2*)(H + (size_t)b * 32768 + (size_t)ih * 2048 + rem)
            : make_double2(0.0, 0.0);
        *(double2*)&Hs[r * 2048 + rem] = v;
    }
    __syncthreads();

    if (ok) {
        f64x4 acc0, acc1;
        #pragma unroll
        for (int q = 0; q < 4; ++q) { acc0[q] = 0.0; acc1[q] = 0.0; }
        const int ow = lm & 7, ohl = lm >> 3;
        #pragma unroll
        for (int kh = 0; kh < 3; ++kh) {
            #pragma unroll
            for (int kw = 0; kw < 3; ++kw) {
                const int tap = kh * 3 + kw;
                const int iw  = 2 * ow - 1 + kw;
                const int ihr = 2 * ohl + kh;
                const int valid = (iw >= 0) & (ihbase + ihr >= 0);
                const int aoff = valid ? (ihr * 2048 + iw * 128 + kq) : 0;
                const double msk = valid ? 1.0 : 0.0;
                const float* wbase = W2 + (size_t)(tap * 128 + kq) * 128 + wn + lm;
                #pragma unroll 4
                for (int ci0 = 0; ci0 < 128; ci0 += 4) {
                    double a  = Hs[aoff + ci0] * msk;
                    double b0 = (double)wbase[ci0 * 128];
                    double b1 = (double)wbase[ci0 * 128 + 16];
                    acc0 = __builtin_amdgcn_mfma_f64_16x16x4f64(a, b0, acc0, 0, 0, 0);
                    acc1 = __builtin_amdgcn_mfma_f64_16x16x4f64(a, b1, acc1, 0, 0, 0);
                }
            }
        }
        #pragma unroll
        for (int s = 0; s < 4; ++s) {
            size_t n = n0 + pm[s];
            int c0 = wn + pn[s];
            X [n * 128 + c0]      = acc0[s];
            Xb[n * 128 + c0]      = f2bf((float)acc0[s]);
            X [n * 128 + c0 + 16] = acc1[s];
            Xb[n * 128 + c0 + 16] = f2bf((float)acc1[s]);
        }
    } else {
        // scalar fallback (never runs on validated HW): 8 outputs/thread
        const int co   = wn + (lane & 31);
        const int half = lane >> 5;
        double facc[8];
        #pragma unroll
        for (int i = 0; i < 8; ++i) facc[i] = 0.0;
        for (int ci = 0; ci < 128; ++ci) {
            #pragma unroll
            for (int kh = 0; kh < 3; ++kh) {
                #pragma unroll
                for (int kw = 0; kw < 3; ++kw) {
                    double wv = (double)W2[(size_t)((kh * 3 + kw) * 128 + ci) * 128 + co];
                    #pragma unroll
                    for (int i = 0; i < 8; ++i) {
                        int m = half * 8 + i;
                        int iw = 2 * (m & 7) - 1 + kw;
                        int ihr = 2 * (m >> 3) + kh;
                        double hv = (iw >= 0 && ihbase + ihr >= 0)
                                  ? Hs[ihr * 2048 + iw * 128 + ci] : 0.0;
                        facc[i] = fma(hv, wv, facc[i]);
                    }
                }
            }
        }
        #pragma unroll
        for (int i = 0; i < 8; ++i) {
            size_t n = n0 + half * 8 + i;
            X [n * 128 + co] = facc[i];
            Xb[n * 128 + co] = f2bf((float)facc[i]);
        }
    }
}

// ---------------------------------------------------------------------------
// k_dist_mfma: bf16 MFMA candidate sweep. Block = 128 rows x 2048-code split;
// grid (64, 8) = 512 blocks (2/CU). Per chunk of 128 codes: 16x16x32 MFMA,
// codes as M, rows as N (D: col=lane&15=row, row=quad*4+reg=code).
// LDS exactly 64 KiB; 16B chunks XOR-swizzled (ch ^= row&15) -> conflict-free.
// Selection: score u = (||c||^2+1024) - 2 x.c > 0; sortable uint key =
// (bits(u) & ~0x7FF) | split-local code idx (11 bits); top-2 per (lane,row)
// class via min/max (no cndmask), then per-row top-2 of 16 via LDS.
// Coverage: bf16 noise sigma~0.05 + trunc <0.5 vs rank gaps ~7-20 -> safe;
// fp64 k_refine picks the exact argmin among the 16 candidates.
__global__ __launch_bounds__(256) void k_dist_mfma(
    const unsigned short* __restrict__ Xb, const unsigned short* __restrict__ Cbb,
    const float* __restrict__ c2f, int* __restrict__ cand)
{
    __shared__ __align__(16) unsigned short Xs[128 * 128];   // 32 KiB
    __shared__ __align__(16) unsigned short Cs[128 * 128];   // 32 KiB
    const int tid   = threadIdx.x;
    const int row0  = blockIdx.x * 128;
    const int split = blockIdx.y;
    const int lane  = tid & 63;
    const int w     = tid >> 6;
    const int quad  = lane >> 4;
    const int lm    = lane & 15;
    const int cw    = (w & 1) * 64;       // wave's code sub-tile
    const int rw    = (w >> 1) * 64;      // wave's row sub-tile

    #pragma unroll
    for (int it = 0; it < 8; ++it) {      // stage X tile once (swizzled)
        int flat = it * 256 + tid;
        int r = flat >> 4, ch = flat & 15;
        *(uint4*)&Xs[r * 128 + (((ch ^ r) & 15) << 3) + (ch & 16 ? 0 : 0)] =
            *(const uint4*)(Xb + (size_t)(row0 + r) * 128 + ch * 8);
    }

    unsigned k1[4], k2[4];
    #pragma unroll
    for (int j = 0; j < 4; ++j) { k1[j] = 0xFFFFFFFFu; k2[j] = 0xFFFFFFFFu; }

    for (int chunk = 0; chunk < 16; ++chunk) {
        const int kb = split * 2048 + chunk * 128;
        if (chunk) __syncthreads();
        #pragma unroll
        for (int it = 0; it < 8; ++it) {  // stage code chunk (swizzled)
            int flat = it * 256 + tid;
            int r = flat >> 4, ch = flat & 15;
            *(uint4*)&Cs[r * 128 + ((ch ^ (r & 15)) << 3)] =
                *(const uint4*)(Cbb + (size_t)(kb + r) * 128 + ch * 8);
        }
        __syncthreads();

        frag_cd acc[4][4];
        #pragma unroll
        for (int i = 0; i < 4; ++i)
            #pragma unroll
            for (int j = 0; j < 4; ++j)
                #pragma unroll
                for (int r = 0; r < 4; ++r) acc[i][j][r] = 0.f;

        #pragma unroll
        for (int kk = 0; kk < 4; ++kk) {
            const int chs = ((kk * 4 + quad) ^ lm) << 3;
            frag_ab a[4], b[4];
            #pragma unroll
            for (int i = 0; i < 4; ++i)
                a[i] = *(const frag_ab*)&Cs[(cw + i * 16 + lm) * 128 + chs];
            #pragma unroll
            for (int j = 0; j < 4; ++j)
                b[j] = *(const frag_ab*)&Xs[(rw + j * 16 + lm) * 128 + chs];
            #pragma unroll
            for (int i = 0; i < 4; ++i)
                #pragma unroll
                for (int j = 0; j < 4; ++j)
                    acc[i][j] = __builtin_amdgcn_mfma_f32_16x16x32_bf16(
                        a[i], b[j], acc[i][j], 0, 0, 0);
        }

        const int ib = chunk * 128 + cw + quad * 4;   // split-local idx base
        #pragma unroll
        for (int i = 0; i < 4; ++i) {
            f32x4 c2v = *(const f32x4*)(c2f + kb + cw + i * 16 + quad * 4);
            #pragma unroll
            for (int j = 0; j < 4; ++j) {
                #pragma unroll
                for (int r = 0; r < 4; ++r) {
                    float u = fmaf(-2.f, acc[i][j][r], c2v[r]);
                    unsigned key = (__float_as_uint(u) & 0xFFFFF800u)
                                 | (unsigned)(ib + i * 16 + r);
                    unsigned nk1 = min(key, k1[j]);
                    k2[j] = min(max(key, k1[j]), k2[j]);
                    k1[j] = nk1;
                }
            }
        }
    }

    // per-row reduce: 8 slots x 2 keys -> top-2 of the split
    __syncthreads();
    uint2* kred = (uint2*)Cs;             // [128 rows][8 slots]
    #pragma unroll
    for (int j = 0; j < 4; ++j)
        kred[(rw + j * 16 + lm) * 8 + (w & 1) * 4 + quad] = make_uint2(k1[j], k2[j]);
    __syncthreads();
    if (tid < 128) {
        unsigned b1 = 0xFFFFFFFFu, b2 = 0xFFFFFFFFu;
        for (int e = 0; e < 8; ++e) {
            uint2 kv = kred[tid * 8 + e];
            unsigned n1 = min(kv.x, b1); b2 = min(max(kv.x, b1), b2); b1 = n1;
            n1 = min(kv.y, b1);          b2 = min(max(kv.y, b1), b2); b1 = n1;
        }
        int base = split * 2048;
        int* o = cand + (size_t)(row0 + tid) * 16 + split * 2;
        o[0] = base + (int)(b1 & 0x7FFu);
        o[1] = base + (int)(b2 & 0x7FFu);
    }
}

// ---------------------------------------------------------------------------
// k_refine: fp64-exact argmin over 16 candidates; quantize; counts; indices.
__global__ __launch_bounds__(256) void k_refine(
    const double* __restrict__ X, const float* __restrict__ cb,
    const int* __restrict__ cand, const float* __restrict__ rnd,
    int* __restrict__ counts, float* __restrict__ quant,
    float* __restrict__ out_mi)
{
    const int wid  = threadIdx.x >> 6;
    const int lane = threadIdx.x & 63;
    const int row  = blockIdx.x * 4 + wid;
    const double x0 = X[(size_t)row * 128 + lane];
    const double x1 = X[(size_t)row * 128 + 64 + lane];
    double bestv = 1e300; int bestk = 0;
    for (int c = 0; c < 16; ++c) {
        int k = cand[(size_t)row * 16 + c] & (KCB - 1);   // defensive clamp
        double t0 = x0 - (double)cb[(size_t)k * 128 + lane];
        double t1 = x1 - (double)cb[(size_t)k * 128 + 64 + lane];
        double s = t0 * t0 + t1 * t1;
        #pragma unroll
        for (int off = 32; off > 0; off >>= 1) s += __shfl_xor(s, off, 64);
        if (s < bestv) { bestv = s; bestk = k; }
    }
    double r0 = (double)rnd[(size_t)row * 128 + lane];
    double r1 = (double)rnd[(size_t)row * 128 + 64 + lane];
    double rs = r0 * r0 + r1 * r1;
    #pragma unroll
    for (int off = 32; off > 0; off >>= 1) rs += __shfl_xor(rs, off, 64);
    double ratio = sqrt(bestv) / sqrt(rs) + 1e-12;
    quant[(size_t)row * 128 + lane]      = (float)(x0 + ratio * r0);
    quant[(size_t)row * 128 + 64 + lane] = (float)(x1 + ratio * r1);
    if (lane == 0) {
        out_mi[row] = (float)bestk;
        atomicAdd(counts + bestk, 1);
    }
}

// ---------------------------------------------------------------------------
// k_perplex: perplexity + new_used (single block)
__global__ __launch_bounds__(256) void k_perplex(
    const int* __restrict__ counts, const int* __restrict__ used_in,
    float* __restrict__ out_used, float* __restrict__ out_perp)
{
    __shared__ double red[256];
    int tid = threadIdx.x;
    double e = 0.0;
    for (int k = tid; k < KCB; k += 256) {
        int c = counts[k];
        out_used[k] = (float)(used_in[k] + c);
        if (c > 0) {
            double p = (double)c / 8192.0;
            e += p * log(p + 1e-12);
        }
    }
    red[tid] = e;
    __syncthreads();
    for (int s = 128; s > 0; s >>= 1) {
        if (tid < s) red[tid] += red[tid + s];
        __syncthreads();
    }
    if (tid == 0) out_perp[0] = (float)exp(-red[0]);
}

// ---------------------------------------------------------------------------
// k_decode: out[b,s2,m] = sum_d2 quant[b*8192 + d2*64 + s2] * W_out[d2,m] + b_out[m]
__global__ __launch_bounds__(256) void k_decode(
    const float* __restrict__ quant, const float* __restrict__ W_out,
    const float* __restrict__ b_out, float* __restrict__ out)
{
    __shared__ float As[8192];             // [d2][s2] (raw reinterpretation!)
    __shared__ float Bs[8192];             // [d2][64 m]
    const int tid = threadIdx.x;
    const int m0  = blockIdx.x * 64;
    const int b   = blockIdx.y;
    #pragma unroll
    for (int it = 0; it < 8; ++it) {
        int flat = it * 1024 + tid * 4;
        *(float4*)&As[flat] = *(const float4*)(quant + (size_t)b * 8192 + flat);
        int d2 = flat >> 6, m = flat & 63;
        *(float4*)&Bs[flat] = *(const float4*)(W_out + (size_t)d2 * 512 + m0 + m);
    }
    __syncthreads();
    const int tx = tid & 15, ty = tid >> 4;
    float acc[4][4];
    #pragma unroll
    for (int i = 0; i < 4; ++i)
        #pragma unroll
        for (int j = 0; j < 4; ++j) acc[i][j] = 0.f;
    #pragma unroll 8
    for (int d2 = 0; d2 < 128; ++d2) {
        float4 a  = *(const float4*)&As[d2 * 64 + ty * 4];
        float4 b4 = *(const float4*)&Bs[d2 * 64 + tx * 4];
        float av[4] = {a.x, a.y, a.z, a.w};
        float bv[4] = {b4.x, b4.y, b4.z, b4.w};
        #pragma unroll
        for (int i = 0; i < 4; ++i)
            #pragma unroll
            for (int j = 0; j < 4; ++j)
                acc[i][j] = fmaf(av[i], bv[j], acc[i][j]);
    }
    float4 bo = *(const float4*)(b_out + m0 + tx * 4);
    float bob[4] = {bo.x, bo.y, bo.z, bo.w};
    #pragma unroll
    for (int i = 0; i < 4; ++i) {
        int s2 = ty * 4 + i;
        float4 o;
        o.x = acc[i][0] + bob[0];
        o.y = acc[i][1] + bob[1];
        o.z = acc[i][2] + bob[2];
        o.w = acc[i][3] + bob[3];
        *(float4*)(out + (size_t)b * 32768 + (size_t)s2 * 512 + m0 + tx * 4) = o;
    }
}

// ---------------------------------------------------------------------------
extern "C" void kernel_launch(void* const* d_in, const int* in_sizes, int n_in,
                              void* d_out, int out_size, void* d_ws, size_t ws_size,
                              hipStream_t stream) {
    const float* first  = (const float*)d_in[0];
    const float* last   = (const float*)d_in[1];
    const float* rnd    = (const float*)d_in[2];
    const float* cb     = (const float*)d_in[3];
    const float* W_in   = (const float*)d_in[4];
    const float* conv_w = (const float*)d_in[6];
    const float* W_out  = (const float*)d_in[8];
    const float* b_out  = (const float*)d_in[9];
    const int*   used   = (const int*)d_in[10];

    float* out      = (float*)d_out;
    float* out_perp = out + 4194304;               // B*64*DIM
    float* out_used = out + 4194305;
    float* out_mi   = out + 4194305 + 16384;

    char* ws = (char*)d_ws;
    double*         H      = (double*)(ws);                 // 33,554,432 B
    double*         X      = (double*)(ws + 33554432);      //  8,388,608 B
    unsigned short* Cbb    = (unsigned short*)(ws + 41943040); // 4,194,304 B
    float*          W2     = (float*) (ws + 46137344);      //    589,824 B
    float*          c2f    = (float*) (ws + 46727168);      //     65,536 B
    int*            cand   = (int*)   (ws + 46792704);      //    524,288 B
    float*          quant  = (float*) (ws + 47316992);      //  4,194,304 B
    int*            counts = (int*)   (ws + 51511296);      //     65,536 B
    unsigned short* Xb     = (unsigned short*)(ws + 51576832); // 2,097,152 B
                                                            // total 53,673,984 B

    hipMemsetAsync(counts, 0, KCB * sizeof(int), stream);
    k_wt<<<576, 256, 0, stream>>>(conv_w, W2);
    k_c2<<<64, 256, 0, stream>>>(cb, c2f);
    k_cbbf<<<2048, 256, 0, stream>>>(cb, Cbb);
    k_encode_gemm<<<1024, 256, 0, stream>>>(last, first, W_in, H);
    k_conv<<<512, 256, 0, stream>>>(H, W2, X, Xb);
    k_dist_mfma<<<dim3(64, 8), 256, 0, stream>>>(Xb, Cbb, c2f, cand);
    k_refine<<<2048, 256, 0, stream>>>(X, cb, cand, rnd, counts, quant, out_mi);
    k_perplex<<<1, 256, 0, stream>>>(counts, used, out_used, out_perp);
    k_decode<<<dim3(8, 128), 256, 0, stream>>>(quant, W_out, b_out, out);
}